// Round 3
// baseline (457.392 us; speedup 1.0000x reference)
//
#include <hip/hip_runtime.h>

#define DD 64
#define RR 12
#define KTOT 832   // 768 (A·Wrel) + 64 (h·(Wself+Wskip))
#define NKS 26     // 832 / 32 k-steps
#define ASTR 840   // LDS A row stride in halfs (420 words ≡ 4 mod 32: even banks)
#define TROWS 32   // nodes per block tile; 1024-thread blocks keep 32 waves/CU
#define EPB2 8192  // edges per block in bucket passes

typedef _Float16 half8v __attribute__((ext_vector_type(8)));
typedef __attribute__((ext_vector_type(4))) float f32x4;

// ---------------- h0 = relu(x * W_emb + b_emb), x is [N,1]; also fp16 copy ----
__global__ void k_h0(const float* __restrict__ x, const float* __restrict__ Wemb,
                     const float* __restrict__ bemb, float* __restrict__ h0,
                     _Float16* __restrict__ h16, int N) {
    int idx = blockIdx.x * blockDim.x + threadIdx.x;
    if (idx >= N * DD) return;
    int n = idx >> 6, d = idx & 63;
    float v = x[n] * Wemb[d] + bemb[d];
    v = v > 0.f ? v : 0.f;
    h0[idx] = v;
    h16[idx] = (_Float16)v;
}

// EW[n*12+r] = (ev, ev*gate)
__global__ void k_sgw(const float* __restrict__ h, const float* __restrict__ q,
                      const float* __restrict__ g, const float* __restrict__ gb,
                      float2* __restrict__ EW, int N) {
    int t = blockIdx.x * blockDim.x + threadIdx.x;
    if (t >= N * RR) return;
    int n = t / RR, r = t - n * RR;
    const float4* hp = (const float4*)(h + (size_t)n * DD);
    const float4* qp = (const float4*)(q + (size_t)r * DD);
    const float4* gp = (const float4*)(g + (size_t)r * DD);
    float sq = 0.f, sg = 0.f;
#pragma unroll
    for (int k = 0; k < 16; k++) {
        float4 hv = hp[k], qv = qp[k], gv = gp[k];
        sq += hv.x * qv.x + hv.y * qv.y + hv.z * qv.z + hv.w * qv.w;
        sg += hv.x * gv.x + hv.y * gv.y + hv.z * gv.z + hv.w * gv.w;
    }
    float sc = sq > 0.f ? sq : 0.01f * sq;       // leaky_relu
    float ev = expf(sc);                          // softmax max-shift invariant
    float gate = 1.f / (1.f + expf(-(sg + gb[0])));
    EW[t] = make_float2(ev, ev * gate);
}

// ---- per-edge weight stream in sorted order: wz[p] = (ev, ev*gate) ----
__global__ void k_ew(const unsigned* __restrict__ epk, const float2* __restrict__ EW,
                     float2* __restrict__ wz, int E) {
    int t = blockIdx.x * blockDim.x + threadIdx.x;
    if (t >= E) return;
    unsigned pk = epk[t];
    int s = (int)(pk & 0xFFFFu);
    int e = (int)((pk >> 16) & 15u);
    wz[t] = EW[(size_t)s * RR + e];
}

// ============ coalesced two-level counting sort by dst ============
// bucket = dst >> 7 (128 nodes per bucket). payload u32 = dlow<<20 | et<<16 | src

__global__ void k_bh(const int* __restrict__ dst, int* __restrict__ bcnt,
                     int E, int nbuck) {
    __shared__ int lh[512];
    int tid = threadIdx.x;
    for (int i = tid; i < 512; i += 512) lh[i] = 0;
    __syncthreads();
    int base = blockIdx.x * EPB2;
    int lim = base + EPB2 < E ? base + EPB2 : E;
    for (int i = base + tid; i < lim; i += 512)
        atomicAdd(&lh[dst[i] >> 7], 1);
    __syncthreads();
    for (int i = tid; i < nbuck; i += 512)
        if (lh[i]) atomicAdd(&bcnt[i], lh[i]);
}

__global__ void k_bscan(const int* __restrict__ bcnt, int* __restrict__ bbase,
                        int* __restrict__ bcur, int nbuck, int E) {
    __shared__ int wsum[8];
    int tid = threadIdx.x, lane = tid & 63, wv = tid >> 6;
    int v = (tid < nbuck) ? bcnt[tid] : 0;
    int incl = v;
#pragma unroll
    for (int d = 1; d < 64; d <<= 1) {
        int t2 = __shfl_up(incl, d);
        if (lane >= d) incl += t2;
    }
    if (lane == 63) wsum[wv] = incl;
    __syncthreads();
    int pre = 0;
#pragma unroll
    for (int w = 0; w < 8; w++) if (w < wv) pre += wsum[w];
    int excl = pre + incl - v;
    if (tid < nbuck) { bbase[tid] = excl; bcur[tid] = excl; }
    if (tid == nbuck - 1) bbase[nbuck] = excl + v;   // == E
}

__global__ void k_bscat(const int* __restrict__ src, const int* __restrict__ dst,
                        const int* __restrict__ et, int* __restrict__ bcur,
                        unsigned* __restrict__ epk2, int E, int nbuck) {
    __shared__ int lh[512];
    __shared__ int lcur[512];
    int tid = threadIdx.x;
    for (int i = tid; i < 512; i += 512) lh[i] = 0;
    __syncthreads();
    int base = blockIdx.x * EPB2;
    int lim = base + EPB2 < E ? base + EPB2 : E;
    for (int i = base + tid; i < lim; i += 512)
        atomicAdd(&lh[dst[i] >> 7], 1);
    __syncthreads();
    for (int i = tid; i < nbuck; i += 512)
        lcur[i] = lh[i] ? atomicAdd(&bcur[i], lh[i]) : 0;
    __syncthreads();
    for (int i = base + tid; i < lim; i += 512) {
        int d = dst[i];
        int pos = atomicAdd(&lcur[d >> 7], 1);
        epk2[pos] = ((unsigned)(d & 127) << 20) | ((unsigned)et[i] << 16) | (unsigned)src[i];
    }
}

__global__ void k_b2(const unsigned* __restrict__ epk2, const int* __restrict__ bbase,
                     unsigned* __restrict__ epk, int* __restrict__ offd,
                     int N, int E) {
    int b = blockIdx.x, tid = threadIdx.x;
    int p0 = bbase[b], p1 = bbase[b + 1], cb = p1 - p0;
    __shared__ int hist[128], cur[128];
    __shared__ unsigned stg[4096];
    if (tid < 128) hist[tid] = 0;
    __syncthreads();
    for (int i = tid; i < cb; i += 256)
        atomicAdd(&hist[(epk2[p0 + i] >> 20) & 127], 1);
    __syncthreads();
    if (tid == 0) {
        int a = 0;
        for (int j = 0; j < 128; j++) { int c = hist[j]; hist[j] = a; a += c; }
    }
    __syncthreads();
    if (tid < 128) {
        cur[tid] = hist[tid];
        int node = b * 128 + tid;
        if (node < N) offd[node] = p0 + hist[tid];
    }
    if (b == 0 && tid == 0) offd[N] = E;
    __syncthreads();
    if (cb <= 4096) {
        for (int i = tid; i < cb; i += 256) {
            unsigned pk = epk2[p0 + i];
            int pos = atomicAdd(&cur[(pk >> 20) & 127], 1);
            stg[pos] = pk & 0xFFFFFu;
        }
        __syncthreads();
        for (int i = tid; i < cb; i += 256) epk[p0 + i] = stg[i];
    } else {   // statistically never; correctness fallback
        for (int i = tid; i < cb; i += 256) {
            unsigned pk = epk2[p0 + i];
            int pos = atomicAdd(&cur[(pk >> 20) & 127], 1);
            epk[p0 + pos] = pk & 0xFFFFFu;
        }
    }
}

// -------- weight prep: blocks 0..25 = B fragments (fp16 hi/lo planes);
//          blocks 26..28 = q/g projection vectors --------
__global__ void k_wprep(const float* __restrict__ Wrel, const float* __restrict__ Wself,
                        const float* __restrict__ Wskip, const float* __restrict__ av,
                        const float* __restrict__ gw,
                        _Float16* __restrict__ Bh, _Float16* __restrict__ Bl,
                        float* __restrict__ q, float* __restrict__ g) {
    int bx = blockIdx.x;
    if (bx < NKS) {
        int t = bx * 256 + threadIdx.x;
        int ks = t >> 8, ct = (t >> 6) & 3, lane = t & 63;
        int col = ct * 16 + (lane & 15);
        int kb = ks * 32 + ((lane >> 4) << 3);
        _Float16* ph = Bh + (size_t)t * 8;
        _Float16* pl = Bl + (size_t)t * 8;
#pragma unroll
        for (int i = 0; i < 8; i++) {
            int k = kb + i;
            float v;
            if (k < 768) v = Wrel[(size_t)k * DD + col];
            else {
                v = Wself[(size_t)(k - 768) * DD + col];
                if (Wskip) v += Wskip[(size_t)(k - 768) * DD + col];
            }
            _Float16 h = (_Float16)v;
            ph[i] = h;
            pl[i] = (_Float16)(v - (float)h);
        }
    } else {
        int t = (bx - NKS) * 256 + threadIdx.x;
        if (t >= RR * DD) return;
        const float* wp = Wrel + (size_t)t * DD;
        float aq = 0.f, ag = 0.f;
#pragma unroll
        for (int e = 0; e < DD; e++) { float w = wp[e]; aq += w * av[e]; ag += w * gw[e]; }
        q[t] = aq; g[t] = ag;
    }
}

// ---------------- fused layer kernel: aggregate -> LDS A-tile -> MFMA ------
// 1024-thread blocks, TROWS=32: 16 waves claim 32 nodes (phase 1), then 4
// waves do MFMA with each B fragment applied to TWO 16-row groups — halves
// chip-wide B-panel L2 traffic vs 16-row tiles at the SAME 32-wave/CU cap.
// Z folded in-register from the coalesced wz float2 stream (no k_zn).
#define AGG_EDGE(ee, wy, hh)                                       \
    switch (ee) {                                                  \
        case 0:  acc[0]  = fmaf(wy, hh, acc[0]);  break;           \
        case 1:  acc[1]  = fmaf(wy, hh, acc[1]);  break;           \
        case 2:  acc[2]  = fmaf(wy, hh, acc[2]);  break;           \
        case 3:  acc[3]  = fmaf(wy, hh, acc[3]);  break;           \
        case 4:  acc[4]  = fmaf(wy, hh, acc[4]);  break;           \
        case 5:  acc[5]  = fmaf(wy, hh, acc[5]);  break;           \
        case 6:  acc[6]  = fmaf(wy, hh, acc[6]);  break;           \
        case 7:  acc[7]  = fmaf(wy, hh, acc[7]);  break;           \
        case 8:  acc[8]  = fmaf(wy, hh, acc[8]);  break;           \
        case 9:  acc[9]  = fmaf(wy, hh, acc[9]);  break;           \
        case 10: acc[10] = fmaf(wy, hh, acc[10]); break;           \
        default: acc[11] = fmaf(wy, hh, acc[11]); break;           \
    }

__global__ void __launch_bounds__(1024, 8)
k_fused(const unsigned* __restrict__ epk, const int* __restrict__ offd,
        const _Float16* __restrict__ hin16, const float2* __restrict__ wz,
        const _Float16* __restrict__ Bh, const _Float16* __restrict__ Bl,
        const float* __restrict__ bias, float* __restrict__ out,
        _Float16* __restrict__ hout16, int N, int act) {
    __shared__ __align__(16) _Float16 At[TROWS * ASTR];
    __shared__ int offs[TROWS + 1];
    __shared__ int claim;
    int tid = threadIdx.x, lane = tid & 63, w = tid >> 6;
    int nb0 = blockIdx.x * TROWS;
    if (tid == 0) claim = 0;
    if (tid < TROWS + 1) {
        int nn = nb0 + tid;
        offs[tid] = (nn <= N) ? offd[nn] : 0;
    }
    __syncthreads();

    // ---- phase 1: 16 waves claim the 32 nodes ----
    for (;;) {
        int t0 = 0;
        if (lane == 0) t0 = atomicAdd(&claim, 1);
        int nl = __builtin_amdgcn_readfirstlane(t0);
        if (nl >= TROWS) break;
        int node = nb0 + nl;
        _Float16* Ar = At + nl * ASTR;
        if (node >= N) {
            for (int k = lane; k < KTOT; k += 64) Ar[k] = (_Float16)0.f;
            continue;
        }
        int p0 = offs[nl];
        int p1 = offs[nl + 1];
        float acc[RR];
#pragma unroll
        for (int r = 0; r < RR; r++) acc[r] = 0.f;
        float zacc = 0.f;
        int p = p0;
        for (; p + 16 <= p1; p += 16) {
            unsigned pk[16];
            float2 wv[16];
            float hv[16];
#pragma unroll
            for (int i = 0; i < 16; i++) pk[i] = epk[p + i];
#pragma unroll
            for (int i = 0; i < 16; i++) wv[i] = wz[p + i];
#pragma unroll
            for (int i = 0; i < 16; i++)
                hv[i] = (float)hin16[(size_t)(pk[i] & 0xFFFFu) * DD + lane];
#pragma unroll
            for (int i = 0; i < 16; i++) {
                int e = __builtin_amdgcn_readfirstlane((int)((pk[i] >> 16) & 15u));
                zacc += wv[i].x;
                AGG_EDGE(e, wv[i].y, hv[i]);
            }
        }
        for (; p + 4 <= p1; p += 4) {
            unsigned pk[4];
            float2 wv[4];
            float hv[4];
#pragma unroll
            for (int i = 0; i < 4; i++) pk[i] = epk[p + i];
#pragma unroll
            for (int i = 0; i < 4; i++) wv[i] = wz[p + i];
#pragma unroll
            for (int i = 0; i < 4; i++)
                hv[i] = (float)hin16[(size_t)(pk[i] & 0xFFFFu) * DD + lane];
#pragma unroll
            for (int i = 0; i < 4; i++) {
                int e = __builtin_amdgcn_readfirstlane((int)((pk[i] >> 16) & 15u));
                zacc += wv[i].x;
                AGG_EDGE(e, wv[i].y, hv[i]);
            }
        }
        for (; p < p1; ++p) {
            unsigned pk = epk[p];
            float2 wzv = wz[p];
            float hv = (float)hin16[(size_t)(pk & 0xFFFFu) * DD + lane];
            int e = __builtin_amdgcn_readfirstlane((int)((pk >> 16) & 15u));
            zacc += wzv.x;
            AGG_EDGE(e, wzv.y, hv);
        }
        float inv = 1.f / (zacc + 1e-16f);
#pragma unroll
        for (int r = 0; r < RR; r++) Ar[r * DD + lane] = (_Float16)(acc[r] * inv);
        Ar[768 + lane] = hin16[(size_t)node * DD + lane];   // self/skip cols
    }
    __syncthreads();

    // ---- phase 2: waves 0-3, each col-tile's B applied to 2 row-groups ----
    if (w < 4) {
        const half8v* Bh8 = (const half8v*)Bh;
        const half8v* Bl8 = (const half8v*)Bl;
        const _Float16* abase = At + (lane & 15) * ASTR + ((lane >> 4) << 3);
        f32x4 accA = {0.f, 0.f, 0.f, 0.f};
        f32x4 accB = {0.f, 0.f, 0.f, 0.f};
#pragma unroll 2
        for (int ks = 0; ks < NKS; ++ks) {
            half8v ah0 = *(const half8v*)(abase + ks * 32);
            half8v ah1 = *(const half8v*)(abase + 16 * ASTR + ks * 32);
            size_t bb = (size_t)(ks * 4 + w) * 64 + lane;
            half8v bh = Bh8[bb];
            half8v bl = Bl8[bb];
            accA = __builtin_amdgcn_mfma_f32_16x16x32_f16(ah0, bh, accA, 0, 0, 0);
            accA = __builtin_amdgcn_mfma_f32_16x16x32_f16(ah0, bl, accA, 0, 0, 0);
            accB = __builtin_amdgcn_mfma_f32_16x16x32_f16(ah1, bh, accB, 0, 0, 0);
            accB = __builtin_amdgcn_mfma_f32_16x16x32_f16(ah1, bl, accB, 0, 0, 0);
        }

        // epilogue: D layout col=lane&15, row=(lane>>4)*4+j
        int colb = lane & 15, kg = lane >> 4;
        int c = w * 16 + colb;
        float bv = bias[c];
#pragma unroll
        for (int j = 0; j < 4; j++) {
            int row = nb0 + kg * 4 + j;
            if (row < N) {
                float v = accA[j] + bv;
                if (act) v = v > 0.f ? v : 0.f;
                out[(size_t)row * DD + c] = v;
                if (hout16) hout16[(size_t)row * DD + c] = (_Float16)v;
            }
            int row2 = nb0 + 16 + kg * 4 + j;
            if (row2 < N) {
                float v = accB[j] + bv;
                if (act) v = v > 0.f ? v : 0.f;
                out[(size_t)row2 * DD + c] = v;
                if (hout16) hout16[(size_t)row2 * DD + c] = (_Float16)v;
            }
        }
    }
}

extern "C" void kernel_launch(void* const* d_in, const int* in_sizes, int n_in,
                              void* d_out, int out_size, void* d_ws, size_t ws_size,
                              hipStream_t stream) {
    const float* x    = (const float*)d_in[0];
    const int*   src  = (const int*)d_in[1];
    const int*   dst  = (const int*)d_in[2];
    const int*   etyp = (const int*)d_in[3];
    const float* Wemb = (const float*)d_in[4];
    const float* bemb = (const float*)d_in[5];
    const int N = in_sizes[0];
    const int E = in_sizes[1];
    const int nbuck = (N + 127) >> 7;
    const int nblk2 = (E + EPB2 - 1) / EPB2;

    const float* Wrel[3];  const float* Wself[3]; const float* bb[3];
    const float* gwv[3];   const float* gbv[3];   const float* av[3];
    for (int l = 0; l < 3; l++) {
        int o = 6 + 6 * l;
        Wrel[l]  = (const float*)d_in[o + 0];
        Wself[l] = (const float*)d_in[o + 1];
        bb[l]    = (const float*)d_in[o + 2];
        gwv[l]   = (const float*)d_in[o + 3];
        gbv[l]   = (const float*)d_in[o + 4];
        av[l]    = (const float*)d_in[o + 5];
    }
    const float* Wskip2 = (const float*)d_in[24];
    const float* Wskip3 = (const float*)d_in[25];

    // ---- workspace ----
    float* p = (float*)d_ws;
    float* h0 = p; p += (size_t)N * DD;
    float* h1 = p; p += (size_t)N * DD;
    float* h2 = p; p += (size_t)N * DD;
    _Float16* h16A = (_Float16*)p; p += (size_t)N * DD / 2;   // fp16 copy (ping)
    _Float16* h16B = (_Float16*)p; p += (size_t)N * DD / 2;   // fp16 copy (pong)
    float2* EW = (float2*)p; p += (size_t)N * RR * 2;
    float* q  = p; p += RR * DD;
    float* g  = p; p += RR * DD;
    _Float16* Bh = (_Float16*)p; p += NKS * 4 * 64 * 8 / 2;
    _Float16* Bl = (_Float16*)p; p += NKS * 4 * 64 * 8 / 2;
    unsigned* epk2 = (unsigned*)p; p += E;
    unsigned* epk  = (unsigned*)p; p += E;
    float2* wzv = (float2*)p; p += (size_t)E * 2;
    int* bcnt  = (int*)p; p += 512;
    int* bbase = (int*)p; p += 516;
    int* bcur  = (int*)p; p += 512;
    int* offd  = (int*)p; p += N + 4;

    const int B = 256;
    k_h0<<<(N * DD + B - 1) / B, B, 0, stream>>>(x, Wemb, bemb, h0, h16A, N);

    // coalesced two-level dst-sort (once; reused by all layers)
    hipMemsetAsync(bcnt, 0, 512 * 4, stream);
    k_bh<<<nblk2, 512, 0, stream>>>(dst, bcnt, E, nbuck);
    k_bscan<<<1, 512, 0, stream>>>(bcnt, bbase, bcur, nbuck, E);
    k_bscat<<<nblk2, 512, 0, stream>>>(src, dst, etyp, bcur, epk2, E, nbuck);
    k_b2<<<nbuck, 256, 0, stream>>>(epk2, bbase, epk, offd, N, E);

    const int fblocks = (N + TROWS - 1) / TROWS;
    // hin (f32) for scores; hin16 for gather; hout16 written for next layer
    auto layer = [&](const float* hin, const _Float16* hin16, float* hout,
                     _Float16* hout16, int l, const float* Wskip, int act) {
        k_wprep<<<NKS + 3, B, 0, stream>>>(Wrel[l], Wself[l], Wskip, av[l], gwv[l],
                                           Bh, Bl, q, g);
        k_sgw<<<(N * RR + B - 1) / B, B, 0, stream>>>(hin, q, g, gbv[l], EW, N);
        k_ew<<<(E + B - 1) / B, B, 0, stream>>>(epk, EW, wzv, E);
        k_fused<<<fblocks, 1024, 0, stream>>>(epk, offd, hin16, wzv, Bh, Bl,
                                              bb[l], hout, hout16, N, act);
    };

    layer(h0, h16A, h1, h16B, 0, nullptr, 1);
    layer(h1, h16B, h2, h16A, 1, Wskip2, 1);
    layer(h2, h16A, (float*)d_out, nullptr, 2, Wskip3, 0);
}

// Round 4
// 364.225 us; speedup vs baseline: 1.2558x; 1.2558x over previous
//
#include <hip/hip_runtime.h>

#define DD 64
#define RR 12
#define KTOT 832   // 768 (A·Wrel) + 64 (h·(Wself+Wskip))
#define NKS 26     // 832 / 32 k-steps
#define ASTR 840   // LDS A row stride in halfs (420 words ≡ 4 mod 32: even banks)
#define TROWS 16   // nodes per block tile — proven geometry, do not change
#define EPB2 8192  // edges per block in bucket passes

typedef _Float16 half8v __attribute__((ext_vector_type(8)));
typedef __attribute__((ext_vector_type(4))) float f32x4;

// ---------------- h0 = relu(x * W_emb + b_emb), x is [N,1]; also fp16 copy ----
__global__ void k_h0(const float* __restrict__ x, const float* __restrict__ Wemb,
                     const float* __restrict__ bemb, float* __restrict__ h0,
                     _Float16* __restrict__ h16, int N) {
    int idx = blockIdx.x * blockDim.x + threadIdx.x;
    if (idx >= N * DD) return;
    int n = idx >> 6, d = idx & 63;
    float v = x[n] * Wemb[d] + bemb[d];
    v = v > 0.f ? v : 0.f;
    h0[idx] = v;
    h16[idx] = (_Float16)v;
}

// EW[n*12+r] = (ev, ev*gate)
__global__ void k_sgw(const float* __restrict__ h, const float* __restrict__ q,
                      const float* __restrict__ g, const float* __restrict__ gb,
                      float2* __restrict__ EW, int N) {
    int t = blockIdx.x * blockDim.x + threadIdx.x;
    if (t >= N * RR) return;
    int n = t / RR, r = t - n * RR;
    const float4* hp = (const float4*)(h + (size_t)n * DD);
    const float4* qp = (const float4*)(q + (size_t)r * DD);
    const float4* gp = (const float4*)(g + (size_t)r * DD);
    float sq = 0.f, sg = 0.f;
#pragma unroll
    for (int k = 0; k < 16; k++) {
        float4 hv = hp[k], qv = qp[k], gv = gp[k];
        sq += hv.x * qv.x + hv.y * qv.y + hv.z * qv.z + hv.w * qv.w;
        sg += hv.x * gv.x + hv.y * gv.y + hv.z * gv.z + hv.w * gv.w;
    }
    float sc = sq > 0.f ? sq : 0.01f * sq;       // leaky_relu
    float ev = expf(sc);                          // softmax max-shift invariant
    float gate = 1.f / (1.f + expf(-(sg + gb[0])));
    EW[t] = make_float2(ev, ev * gate);
}

// ---- per-edge weight stream in sorted order: wz[p] = (ev, ev*gate) ----
__global__ void k_ew(const unsigned* __restrict__ epk, const float2* __restrict__ EW,
                     float2* __restrict__ wz, int E) {
    int t = blockIdx.x * blockDim.x + threadIdx.x;
    if (t >= E) return;
    unsigned pk = epk[t];
    int s = (int)(pk & 0xFFFFu);
    int e = (int)((pk >> 16) & 15u);
    wz[t] = EW[(size_t)s * RR + e];
}

// ============ coalesced two-level counting sort by dst ============
// bucket = dst >> 7 (128 nodes per bucket). payload u32 = dlow<<20 | et<<16 | src

__global__ void k_bh(const int* __restrict__ dst, int* __restrict__ bcnt,
                     int E, int nbuck) {
    __shared__ int lh[512];
    int tid = threadIdx.x;
    for (int i = tid; i < 512; i += 512) lh[i] = 0;
    __syncthreads();
    int base = blockIdx.x * EPB2;
    int lim = base + EPB2 < E ? base + EPB2 : E;
    for (int i = base + tid; i < lim; i += 512)
        atomicAdd(&lh[dst[i] >> 7], 1);
    __syncthreads();
    for (int i = tid; i < nbuck; i += 512)
        if (lh[i]) atomicAdd(&bcnt[i], lh[i]);
}

__global__ void k_bscan(const int* __restrict__ bcnt, int* __restrict__ bbase,
                        int* __restrict__ bcur, int nbuck, int E) {
    __shared__ int wsum[8];
    int tid = threadIdx.x, lane = tid & 63, wv = tid >> 6;
    int v = (tid < nbuck) ? bcnt[tid] : 0;
    int incl = v;
#pragma unroll
    for (int d = 1; d < 64; d <<= 1) {
        int t2 = __shfl_up(incl, d);
        if (lane >= d) incl += t2;
    }
    if (lane == 63) wsum[wv] = incl;
    __syncthreads();
    int pre = 0;
#pragma unroll
    for (int w = 0; w < 8; w++) if (w < wv) pre += wsum[w];
    int excl = pre + incl - v;
    if (tid < nbuck) { bbase[tid] = excl; bcur[tid] = excl; }
    if (tid == nbuck - 1) bbase[nbuck] = excl + v;   // == E
}

__global__ void k_bscat(const int* __restrict__ src, const int* __restrict__ dst,
                        const int* __restrict__ et, int* __restrict__ bcur,
                        unsigned* __restrict__ epk2, int E, int nbuck) {
    __shared__ int lh[512];
    __shared__ int lcur[512];
    int tid = threadIdx.x;
    for (int i = tid; i < 512; i += 512) lh[i] = 0;
    __syncthreads();
    int base = blockIdx.x * EPB2;
    int lim = base + EPB2 < E ? base + EPB2 : E;
    for (int i = base + tid; i < lim; i += 512)
        atomicAdd(&lh[dst[i] >> 7], 1);
    __syncthreads();
    for (int i = tid; i < nbuck; i += 512)
        lcur[i] = lh[i] ? atomicAdd(&bcur[i], lh[i]) : 0;
    __syncthreads();
    for (int i = base + tid; i < lim; i += 512) {
        int d = dst[i];
        int pos = atomicAdd(&lcur[d >> 7], 1);
        epk2[pos] = ((unsigned)(d & 127) << 20) | ((unsigned)et[i] << 16) | (unsigned)src[i];
    }
}

__global__ void k_b2(const unsigned* __restrict__ epk2, const int* __restrict__ bbase,
                     unsigned* __restrict__ epk, int* __restrict__ offd,
                     int N, int E) {
    int b = blockIdx.x, tid = threadIdx.x;
    int p0 = bbase[b], p1 = bbase[b + 1], cb = p1 - p0;
    __shared__ int hist[128], cur[128];
    __shared__ unsigned stg[4096];
    if (tid < 128) hist[tid] = 0;
    __syncthreads();
    for (int i = tid; i < cb; i += 256)
        atomicAdd(&hist[(epk2[p0 + i] >> 20) & 127], 1);
    __syncthreads();
    if (tid == 0) {
        int a = 0;
        for (int j = 0; j < 128; j++) { int c = hist[j]; hist[j] = a; a += c; }
    }
    __syncthreads();
    if (tid < 128) {
        cur[tid] = hist[tid];
        int node = b * 128 + tid;
        if (node < N) offd[node] = p0 + hist[tid];
    }
    if (b == 0 && tid == 0) offd[N] = E;
    __syncthreads();
    if (cb <= 4096) {
        for (int i = tid; i < cb; i += 256) {
            unsigned pk = epk2[p0 + i];
            int pos = atomicAdd(&cur[(pk >> 20) & 127], 1);
            stg[pos] = pk & 0xFFFFFu;
        }
        __syncthreads();
        for (int i = tid; i < cb; i += 256) epk[p0 + i] = stg[i];
    } else {   // statistically never; correctness fallback
        for (int i = tid; i < cb; i += 256) {
            unsigned pk = epk2[p0 + i];
            int pos = atomicAdd(&cur[(pk >> 20) & 127], 1);
            epk[p0 + pos] = pk & 0xFFFFFu;
        }
    }
}

// -------- weight prep: blocks 0..25 = B fragments (fp16 hi/lo planes);
//          blocks 26..28 = q/g projection vectors --------
__global__ void k_wprep(const float* __restrict__ Wrel, const float* __restrict__ Wself,
                        const float* __restrict__ Wskip, const float* __restrict__ av,
                        const float* __restrict__ gw,
                        _Float16* __restrict__ Bh, _Float16* __restrict__ Bl,
                        float* __restrict__ q, float* __restrict__ g) {
    int bx = blockIdx.x;
    if (bx < NKS) {
        int t = bx * 256 + threadIdx.x;
        int ks = t >> 8, ct = (t >> 6) & 3, lane = t & 63;
        int col = ct * 16 + (lane & 15);
        int kb = ks * 32 + ((lane >> 4) << 3);
        _Float16* ph = Bh + (size_t)t * 8;
        _Float16* pl = Bl + (size_t)t * 8;
#pragma unroll
        for (int i = 0; i < 8; i++) {
            int k = kb + i;
            float v;
            if (k < 768) v = Wrel[(size_t)k * DD + col];
            else {
                v = Wself[(size_t)(k - 768) * DD + col];
                if (Wskip) v += Wskip[(size_t)(k - 768) * DD + col];
            }
            _Float16 h = (_Float16)v;
            ph[i] = h;
            pl[i] = (_Float16)(v - (float)h);
        }
    } else {
        int t = (bx - NKS) * 256 + threadIdx.x;
        if (t >= RR * DD) return;
        const float* wp = Wrel + (size_t)t * DD;
        float aq = 0.f, ag = 0.f;
#pragma unroll
        for (int e = 0; e < DD; e++) { float w = wp[e]; aq += w * av[e]; ag += w * gw[e]; }
        q[t] = aq; g[t] = ag;
    }
}

// ---------------- fused layer kernel: aggregate -> LDS A-tile -> MFMA ------
// Proven geometry: 512 threads, TROWS=16, At 27 KB. Phase 1 per-edge loop with
// in-register Z from the coalesced wz float2 stream. Phase 2 K-split: waves
// w and w+4 share col-tile (w&3), each doing 13 of 26 k-steps; partials of
// waves 4-7 land in a SEPARATE 4 KB LDS buffer (no At aliasing), combined by
// waves 0-3 after one barrier.
#define AGG_EDGE(ee, wy, hh)                                       \
    switch (ee) {                                                  \
        case 0:  acc[0]  = fmaf(wy, hh, acc[0]);  break;           \
        case 1:  acc[1]  = fmaf(wy, hh, acc[1]);  break;           \
        case 2:  acc[2]  = fmaf(wy, hh, acc[2]);  break;           \
        case 3:  acc[3]  = fmaf(wy, hh, acc[3]);  break;           \
        case 4:  acc[4]  = fmaf(wy, hh, acc[4]);  break;           \
        case 5:  acc[5]  = fmaf(wy, hh, acc[5]);  break;           \
        case 6:  acc[6]  = fmaf(wy, hh, acc[6]);  break;           \
        case 7:  acc[7]  = fmaf(wy, hh, acc[7]);  break;           \
        case 8:  acc[8]  = fmaf(wy, hh, acc[8]);  break;           \
        case 9:  acc[9]  = fmaf(wy, hh, acc[9]);  break;           \
        case 10: acc[10] = fmaf(wy, hh, acc[10]); break;           \
        default: acc[11] = fmaf(wy, hh, acc[11]); break;           \
    }

__global__ void __launch_bounds__(512, 8)
k_fused(const unsigned* __restrict__ epk, const int* __restrict__ offd,
        const _Float16* __restrict__ hin16, const float2* __restrict__ wz,
        const _Float16* __restrict__ Bh, const _Float16* __restrict__ Bl,
        const float* __restrict__ bias, float* __restrict__ out,
        _Float16* __restrict__ hout16, int N, int act) {
    __shared__ __align__(16) _Float16 At[TROWS * ASTR];
    __shared__ __align__(16) f32x4 Pp[4 * 64];   // K-split partials, 4 KB
    __shared__ int offs[TROWS + 1];
    __shared__ int claim;
    int tid = threadIdx.x, lane = tid & 63, w = tid >> 6;
    int nb0 = blockIdx.x * TROWS;
    if (tid == 0) claim = 0;
    if (tid < TROWS + 1) {
        int nn = nb0 + tid;
        offs[tid] = (nn <= N) ? offd[nn] : 0;
    }
    __syncthreads();

    // ---- phase 1: waves claim nodes until the tile is done ----
    for (;;) {
        int t0 = 0;
        if (lane == 0) t0 = atomicAdd(&claim, 1);
        int nl = __builtin_amdgcn_readfirstlane(t0);
        if (nl >= TROWS) break;
        int node = nb0 + nl;
        _Float16* Ar = At + nl * ASTR;
        if (node >= N) {
            for (int k = lane; k < KTOT; k += 64) Ar[k] = (_Float16)0.f;
            continue;
        }
        int p0 = __builtin_amdgcn_readfirstlane(offs[nl]);
        int p1 = __builtin_amdgcn_readfirstlane(offs[nl + 1]);
        float acc[RR];
#pragma unroll
        for (int r = 0; r < RR; r++) acc[r] = 0.f;
        float zacc = 0.f;
        int p = p0;
        for (; p + 16 <= p1; p += 16) {
            unsigned pk[16];
            float2 wv[16];
            float hv[16];
#pragma unroll
            for (int i = 0; i < 16; i++) pk[i] = epk[p + i];
#pragma unroll
            for (int i = 0; i < 16; i++) wv[i] = wz[p + i];
#pragma unroll
            for (int i = 0; i < 16; i++)
                hv[i] = (float)hin16[(size_t)(pk[i] & 0xFFFFu) * DD + lane];
#pragma unroll
            for (int i = 0; i < 16; i++) {
                int e = __builtin_amdgcn_readfirstlane((int)((pk[i] >> 16) & 15u));
                zacc += wv[i].x;
                AGG_EDGE(e, wv[i].y, hv[i]);
            }
        }
        for (; p + 4 <= p1; p += 4) {
            unsigned pk[4];
            float2 wv[4];
            float hv[4];
#pragma unroll
            for (int i = 0; i < 4; i++) pk[i] = epk[p + i];
#pragma unroll
            for (int i = 0; i < 4; i++) wv[i] = wz[p + i];
#pragma unroll
            for (int i = 0; i < 4; i++)
                hv[i] = (float)hin16[(size_t)(pk[i] & 0xFFFFu) * DD + lane];
#pragma unroll
            for (int i = 0; i < 4; i++) {
                int e = __builtin_amdgcn_readfirstlane((int)((pk[i] >> 16) & 15u));
                zacc += wv[i].x;
                AGG_EDGE(e, wv[i].y, hv[i]);
            }
        }
        for (; p < p1; ++p) {
            unsigned pk = epk[p];
            float2 wzv = wz[p];
            float hv = (float)hin16[(size_t)(pk & 0xFFFFu) * DD + lane];
            int e = __builtin_amdgcn_readfirstlane((int)((pk >> 16) & 15u));
            zacc += wzv.x;
            AGG_EDGE(e, wzv.y, hv);
        }
        float inv = 1.f / (zacc + 1e-16f);
#pragma unroll
        for (int r = 0; r < RR; r++) Ar[r * DD + lane] = (_Float16)(acc[r] * inv);
        Ar[768 + lane] = hin16[(size_t)node * DD + lane];   // self/skip cols
    }
    __syncthreads();

    // ---- phase 2: all 8 waves; K-split pairs (w, w+4) share col-tile w&3 ----
    {
        const half8v* Bh8 = (const half8v*)Bh;
        const half8v* Bl8 = (const half8v*)Bl;
        int cw = w & 3, ksel = w >> 2;
        const _Float16* abase = At + (lane & 15) * ASTR + ((lane >> 4) << 3);
        f32x4 acc0 = {0.f, 0.f, 0.f, 0.f};
        int k0 = ksel * 13;
#pragma unroll
        for (int i = 0; i < 13; ++i) {
            int ks = k0 + i;
            half8v ah = *(const half8v*)(abase + ks * 32);
            size_t bb = (size_t)(ks * 4 + cw) * 64 + lane;
            half8v bh = Bh8[bb];
            half8v bl = Bl8[bb];
            acc0 = __builtin_amdgcn_mfma_f32_16x16x32_f16(ah, bh, acc0, 0, 0, 0);
            acc0 = __builtin_amdgcn_mfma_f32_16x16x32_f16(ah, bl, acc0, 0, 0, 0);
        }
        if (w >= 4) Pp[cw * 64 + lane] = acc0;
        __syncthreads();
        if (w < 4) {
            f32x4 po = Pp[cw * 64 + lane];
            acc0[0] += po[0]; acc0[1] += po[1]; acc0[2] += po[2]; acc0[3] += po[3];

            // epilogue: D layout col=lane&15, row=(lane>>4)*4+j
            int colb = lane & 15, kg = lane >> 4;
            int c = cw * 16 + colb;
            float bv = bias[c];
#pragma unroll
            for (int j = 0; j < 4; j++) {
                int row = nb0 + kg * 4 + j;
                if (row < N) {
                    float v = acc0[j] + bv;
                    if (act) v = v > 0.f ? v : 0.f;
                    out[(size_t)row * DD + c] = v;
                    if (hout16) hout16[(size_t)row * DD + c] = (_Float16)v;
                }
            }
        }
    }
}

extern "C" void kernel_launch(void* const* d_in, const int* in_sizes, int n_in,
                              void* d_out, int out_size, void* d_ws, size_t ws_size,
                              hipStream_t stream) {
    const float* x    = (const float*)d_in[0];
    const int*   src  = (const int*)d_in[1];
    const int*   dst  = (const int*)d_in[2];
    const int*   etyp = (const int*)d_in[3];
    const float* Wemb = (const float*)d_in[4];
    const float* bemb = (const float*)d_in[5];
    const int N = in_sizes[0];
    const int E = in_sizes[1];
    const int nbuck = (N + 127) >> 7;
    const int nblk2 = (E + EPB2 - 1) / EPB2;

    const float* Wrel[3];  const float* Wself[3]; const float* bb[3];
    const float* gwv[3];   const float* gbv[3];   const float* av[3];
    for (int l = 0; l < 3; l++) {
        int o = 6 + 6 * l;
        Wrel[l]  = (const float*)d_in[o + 0];
        Wself[l] = (const float*)d_in[o + 1];
        bb[l]    = (const float*)d_in[o + 2];
        gwv[l]   = (const float*)d_in[o + 3];
        gbv[l]   = (const float*)d_in[o + 4];
        av[l]    = (const float*)d_in[o + 5];
    }
    const float* Wskip[3] = { nullptr, (const float*)d_in[24], (const float*)d_in[25] };

    // ---- workspace ----
    float* p = (float*)d_ws;
    float* h0 = p; p += (size_t)N * DD;
    float* h1 = p; p += (size_t)N * DD;
    float* h2 = p; p += (size_t)N * DD;
    _Float16* h16A = (_Float16*)p; p += (size_t)N * DD / 2;   // fp16 copy (ping)
    _Float16* h16B = (_Float16*)p; p += (size_t)N * DD / 2;   // fp16 copy (pong)
    float2* EW = (float2*)p; p += (size_t)N * RR * 2;
    float* qv3[3]; float* gv3[3]; _Float16* Bh3[3]; _Float16* Bl3[3];
    for (int l = 0; l < 3; l++) {
        qv3[l] = p; p += RR * DD;
        gv3[l] = p; p += RR * DD;
        Bh3[l] = (_Float16*)p; p += NKS * 4 * 64 * 8 / 2;
        Bl3[l] = (_Float16*)p; p += NKS * 4 * 64 * 8 / 2;
    }
    unsigned* epk2 = (unsigned*)p; p += E;
    unsigned* epk  = (unsigned*)p; p += E;
    float2* wzv = (float2*)p; p += (size_t)E * 2;
    int* bcnt  = (int*)p; p += 512;
    int* bbase = (int*)p; p += 516;
    int* bcur  = (int*)p; p += 512;
    int* offd  = (int*)p; p += N + 4;

    const int B = 256;

    // weight prep for all 3 layers upfront (independent of h)
    for (int l = 0; l < 3; l++)
        k_wprep<<<NKS + 3, B, 0, stream>>>(Wrel[l], Wself[l], Wskip[l], av[l], gwv[l],
                                           Bh3[l], Bl3[l], qv3[l], gv3[l]);

    k_h0<<<(N * DD + B - 1) / B, B, 0, stream>>>(x, Wemb, bemb, h0, h16A, N);

    // coalesced two-level dst-sort (once; reused by all layers)
    hipMemsetAsync(bcnt, 0, 512 * 4, stream);
    k_bh<<<nblk2, 512, 0, stream>>>(dst, bcnt, E, nbuck);
    k_bscan<<<1, 512, 0, stream>>>(bcnt, bbase, bcur, nbuck, E);
    k_bscat<<<nblk2, 512, 0, stream>>>(src, dst, etyp, bcur, epk2, E, nbuck);
    k_b2<<<nbuck, 256, 0, stream>>>(epk2, bbase, epk, offd, N, E);

    const int fblocks = (N + TROWS - 1) / TROWS;
    // hin (f32) for scores; hin16 for gather; hout16 written for next layer
    auto layer = [&](const float* hin, const _Float16* hin16, float* hout,
                     _Float16* hout16, int l, int act) {
        k_sgw<<<(N * RR + B - 1) / B, B, 0, stream>>>(hin, qv3[l], gv3[l], gbv[l], EW, N);
        k_ew<<<(E + B - 1) / B, B, 0, stream>>>(epk, EW, wzv, E);
        k_fused<<<fblocks, 512, 0, stream>>>(epk, offd, hin16, wzv, Bh3[l], Bl3[l],
                                             bb[l], hout, hout16, N, act);
    };

    layer(h0, h16A, h1, h16B, 0, 1);
    layer(h1, h16B, h2, h16A, 1, 1);
    layer(h2, h16A, (float*)d_out, nullptr, 2, 0);
}

// Round 5
// 326.210 us; speedup vs baseline: 1.4021x; 1.1165x over previous
//
#include <hip/hip_runtime.h>

#define DD 64
#define RR 12
#define KTOT 832   // 768 (A·Wrel) + 64 (h·(Wself+Wskip))
#define NKS 26     // 832 / 32 k-steps
#define ASTR 840   // LDS A row stride in halfs (420 words ≡ 4 mod 32: even banks)
#define TROWS 16   // nodes per block tile — proven geometry, do not change
#define EPB2 8192  // edges per block in bucket passes

typedef _Float16 half8v __attribute__((ext_vector_type(8)));
typedef __attribute__((ext_vector_type(4))) float f32x4;

// ---------------- h0 = relu(x * W_emb + b_emb), x is [N,1]; also fp16 copy ----
__global__ void k_h0(const float* __restrict__ x, const float* __restrict__ Wemb,
                     const float* __restrict__ bemb, float* __restrict__ h0,
                     _Float16* __restrict__ h16, int N) {
    int idx = blockIdx.x * blockDim.x + threadIdx.x;
    if (idx >= N * DD) return;
    int n = idx >> 6, d = idx & 63;
    float v = x[n] * Wemb[d] + bemb[d];
    v = v > 0.f ? v : 0.f;
    h0[idx] = v;
    h16[idx] = (_Float16)v;
}

// EW[n*12+r] = (ev, ev*gate) — used only for layer 1 (from h0)
__global__ void k_sgw(const float* __restrict__ h, const float* __restrict__ q,
                      const float* __restrict__ g, const float* __restrict__ gb,
                      float2* __restrict__ EW, int N) {
    int t = blockIdx.x * blockDim.x + threadIdx.x;
    if (t >= N * RR) return;
    int n = t / RR, r = t - n * RR;
    const float4* hp = (const float4*)(h + (size_t)n * DD);
    const float4* qp = (const float4*)(q + (size_t)r * DD);
    const float4* gp = (const float4*)(g + (size_t)r * DD);
    float sq = 0.f, sg = 0.f;
#pragma unroll
    for (int k = 0; k < 16; k++) {
        float4 hv = hp[k], qv = qp[k], gv = gp[k];
        sq += hv.x * qv.x + hv.y * qv.y + hv.z * qv.z + hv.w * qv.w;
        sg += hv.x * gv.x + hv.y * gv.y + hv.z * gv.z + hv.w * gv.w;
    }
    float sc = sq > 0.f ? sq : 0.01f * sq;       // leaky_relu
    float ev = expf(sc);                          // softmax max-shift invariant
    float gate = 1.f / (1.f + expf(-(sg + gb[0])));
    EW[t] = make_float2(ev, ev * gate);
}

// ---- per-edge weight stream in sorted order: wz[p] = (ev, ev*gate) ----
__global__ void k_ew(const unsigned* __restrict__ epk, const float2* __restrict__ EW,
                     float2* __restrict__ wz, int E) {
    int t = blockIdx.x * blockDim.x + threadIdx.x;
    if (t >= E) return;
    unsigned pk = epk[t];
    int s = (int)(pk & 0xFFFFu);
    int e = (int)((pk >> 16) & 15u);
    wz[t] = EW[(size_t)s * RR + e];
}

// ============ coalesced two-level counting sort by dst ============
// bucket = dst >> 7 (128 nodes per bucket). payload u32 = dlow<<20 | et<<16 | src

__global__ void k_bh(const int* __restrict__ dst, int* __restrict__ bcnt,
                     int E, int nbuck) {
    __shared__ int lh[512];
    int tid = threadIdx.x;
    for (int i = tid; i < 512; i += 512) lh[i] = 0;
    __syncthreads();
    int base = blockIdx.x * EPB2;
    int lim = base + EPB2 < E ? base + EPB2 : E;
    for (int i = base + tid; i < lim; i += 512)
        atomicAdd(&lh[dst[i] >> 7], 1);
    __syncthreads();
    for (int i = tid; i < nbuck; i += 512)
        if (lh[i]) atomicAdd(&bcnt[i], lh[i]);
}

__global__ void k_bscan(const int* __restrict__ bcnt, int* __restrict__ bbase,
                        int* __restrict__ bcur, int nbuck, int E) {
    __shared__ int wsum[8];
    int tid = threadIdx.x, lane = tid & 63, wv = tid >> 6;
    int v = (tid < nbuck) ? bcnt[tid] : 0;
    int incl = v;
#pragma unroll
    for (int d = 1; d < 64; d <<= 1) {
        int t2 = __shfl_up(incl, d);
        if (lane >= d) incl += t2;
    }
    if (lane == 63) wsum[wv] = incl;
    __syncthreads();
    int pre = 0;
#pragma unroll
    for (int w = 0; w < 8; w++) if (w < wv) pre += wsum[w];
    int excl = pre + incl - v;
    if (tid < nbuck) { bbase[tid] = excl; bcur[tid] = excl; }
    if (tid == nbuck - 1) bbase[nbuck] = excl + v;   // == E
}

__global__ void k_bscat(const int* __restrict__ src, const int* __restrict__ dst,
                        const int* __restrict__ et, int* __restrict__ bcur,
                        unsigned* __restrict__ epk2, int E, int nbuck) {
    __shared__ int lh[512];
    __shared__ int lcur[512];
    int tid = threadIdx.x;
    for (int i = tid; i < 512; i += 512) lh[i] = 0;
    __syncthreads();
    int base = blockIdx.x * EPB2;
    int lim = base + EPB2 < E ? base + EPB2 : E;
    for (int i = base + tid; i < lim; i += 512)
        atomicAdd(&lh[dst[i] >> 7], 1);
    __syncthreads();
    for (int i = tid; i < nbuck; i += 512)
        lcur[i] = lh[i] ? atomicAdd(&bcur[i], lh[i]) : 0;
    __syncthreads();
    for (int i = base + tid; i < lim; i += 512) {
        int d = dst[i];
        int pos = atomicAdd(&lcur[d >> 7], 1);
        epk2[pos] = ((unsigned)(d & 127) << 20) | ((unsigned)et[i] << 16) | (unsigned)src[i];
    }
}

__global__ void k_b2(const unsigned* __restrict__ epk2, const int* __restrict__ bbase,
                     unsigned* __restrict__ epk, int* __restrict__ offd,
                     int N, int E) {
    int b = blockIdx.x, tid = threadIdx.x;
    int p0 = bbase[b], p1 = bbase[b + 1], cb = p1 - p0;
    __shared__ int hist[128], cur[128];
    __shared__ unsigned stg[4096];
    if (tid < 128) hist[tid] = 0;
    __syncthreads();
    for (int i = tid; i < cb; i += 256)
        atomicAdd(&hist[(epk2[p0 + i] >> 20) & 127], 1);
    __syncthreads();
    if (tid == 0) {
        int a = 0;
        for (int j = 0; j < 128; j++) { int c = hist[j]; hist[j] = a; a += c; }
    }
    __syncthreads();
    if (tid < 128) {
        cur[tid] = hist[tid];
        int node = b * 128 + tid;
        if (node < N) offd[node] = p0 + hist[tid];
    }
    if (b == 0 && tid == 0) offd[N] = E;
    __syncthreads();
    if (cb <= 4096) {
        for (int i = tid; i < cb; i += 256) {
            unsigned pk = epk2[p0 + i];
            int pos = atomicAdd(&cur[(pk >> 20) & 127], 1);
            stg[pos] = pk & 0xFFFFFu;
        }
        __syncthreads();
        for (int i = tid; i < cb; i += 256) epk[p0 + i] = stg[i];
    } else {   // statistically never; correctness fallback
        for (int i = tid; i < cb; i += 256) {
            unsigned pk = epk2[p0 + i];
            int pos = atomicAdd(&cur[(pk >> 20) & 127], 1);
            epk[p0 + pos] = pk & 0xFFFFFu;
        }
    }
}

// -------- weight prep: blocks 0..25 = B fragments (fp16 hi/lo planes);
//          blocks 26..28 = q/g projection vectors --------
__global__ void k_wprep(const float* __restrict__ Wrel, const float* __restrict__ Wself,
                        const float* __restrict__ Wskip, const float* __restrict__ av,
                        const float* __restrict__ gw,
                        _Float16* __restrict__ Bh, _Float16* __restrict__ Bl,
                        float* __restrict__ q, float* __restrict__ g) {
    int bx = blockIdx.x;
    if (bx < NKS) {
        int t = bx * 256 + threadIdx.x;
        int ks = t >> 8, ct = (t >> 6) & 3, lane = t & 63;
        int col = ct * 16 + (lane & 15);
        int kb = ks * 32 + ((lane >> 4) << 3);
        _Float16* ph = Bh + (size_t)t * 8;
        _Float16* pl = Bl + (size_t)t * 8;
#pragma unroll
        for (int i = 0; i < 8; i++) {
            int k = kb + i;
            float v;
            if (k < 768) v = Wrel[(size_t)k * DD + col];
            else {
                v = Wself[(size_t)(k - 768) * DD + col];
                if (Wskip) v += Wskip[(size_t)(k - 768) * DD + col];
            }
            _Float16 h = (_Float16)v;
            ph[i] = h;
            pl[i] = (_Float16)(v - (float)h);
        }
    } else {
        int t = (bx - NKS) * 256 + threadIdx.x;
        if (t >= RR * DD) return;
        const float* wp = Wrel + (size_t)t * DD;
        float aq = 0.f, ag = 0.f;
#pragma unroll
        for (int e = 0; e < DD; e++) { float w = wp[e]; aq += w * av[e]; ag += w * gw[e]; }
        q[t] = aq; g[t] = ag;
    }
}

// ---------------- fused layer kernel: aggregate -> LDS A-tile -> MFMA ------
// Proven geometry: 512 threads, TROWS=16, At ~27 KB, phase 2 waves 0-3 only.
// New: epilogue computes the NEXT layer's (ev, ev*gate) table from the fp32
// output tile staged in 4 KB LDS (kills k_sgw for layers 2-3 and the f32
// h1/h2 writes entirely).
#define AGG_EDGE(ee, wy, hh)                                       \
    switch (ee) {                                                  \
        case 0:  acc[0]  = fmaf(wy, hh, acc[0]);  break;           \
        case 1:  acc[1]  = fmaf(wy, hh, acc[1]);  break;           \
        case 2:  acc[2]  = fmaf(wy, hh, acc[2]);  break;           \
        case 3:  acc[3]  = fmaf(wy, hh, acc[3]);  break;           \
        case 4:  acc[4]  = fmaf(wy, hh, acc[4]);  break;           \
        case 5:  acc[5]  = fmaf(wy, hh, acc[5]);  break;           \
        case 6:  acc[6]  = fmaf(wy, hh, acc[6]);  break;           \
        case 7:  acc[7]  = fmaf(wy, hh, acc[7]);  break;           \
        case 8:  acc[8]  = fmaf(wy, hh, acc[8]);  break;           \
        case 9:  acc[9]  = fmaf(wy, hh, acc[9]);  break;           \
        case 10: acc[10] = fmaf(wy, hh, acc[10]); break;           \
        default: acc[11] = fmaf(wy, hh, acc[11]); break;           \
    }

__global__ void __launch_bounds__(512, 8)
k_fused(const unsigned* __restrict__ epk, const int* __restrict__ offd,
        const _Float16* __restrict__ hin16, const float2* __restrict__ wz,
        const _Float16* __restrict__ Bh, const _Float16* __restrict__ Bl,
        const float* __restrict__ bias, float* __restrict__ out,
        _Float16* __restrict__ hout16, int N, int act,
        const float* __restrict__ qn, const float* __restrict__ gn,
        const float* __restrict__ gbn, float2* __restrict__ EWn) {
    __shared__ __align__(16) _Float16 At[TROWS * ASTR];
    __shared__ float Hf[TROWS * 65];             // fp32 out tile for EW epilogue
    __shared__ int offs[TROWS + 1];
    __shared__ int claim;
    int tid = threadIdx.x, lane = tid & 63, w = tid >> 6;
    int nb0 = blockIdx.x * TROWS;
    if (tid == 0) claim = 0;
    if (tid < TROWS + 1) {
        int nn = nb0 + tid;
        offs[tid] = (nn <= N) ? offd[nn] : 0;
    }
    __syncthreads();

    // ---- phase 1: waves claim nodes until the tile is done ----
    for (;;) {
        int t0 = 0;
        if (lane == 0) t0 = atomicAdd(&claim, 1);
        int nl = __builtin_amdgcn_readfirstlane(t0);
        if (nl >= TROWS) break;
        int node = nb0 + nl;
        _Float16* Ar = At + nl * ASTR;
        if (node >= N) {
            for (int k = lane; k < KTOT; k += 64) Ar[k] = (_Float16)0.f;
            continue;
        }
        int p0 = __builtin_amdgcn_readfirstlane(offs[nl]);
        int p1 = __builtin_amdgcn_readfirstlane(offs[nl + 1]);
        float acc[RR];
#pragma unroll
        for (int r = 0; r < RR; r++) acc[r] = 0.f;
        float zacc = 0.f;
        int p = p0;
        for (; p + 16 <= p1; p += 16) {
            unsigned pk[16];
            float2 wv[16];
            float hv[16];
#pragma unroll
            for (int i = 0; i < 16; i++) pk[i] = epk[p + i];
#pragma unroll
            for (int i = 0; i < 16; i++) wv[i] = wz[p + i];
#pragma unroll
            for (int i = 0; i < 16; i++)
                hv[i] = (float)hin16[(size_t)(pk[i] & 0xFFFFu) * DD + lane];
#pragma unroll
            for (int i = 0; i < 16; i++) {
                int e = __builtin_amdgcn_readfirstlane((int)((pk[i] >> 16) & 15u));
                zacc += wv[i].x;
                AGG_EDGE(e, wv[i].y, hv[i]);
            }
        }
        for (; p + 4 <= p1; p += 4) {
            unsigned pk[4];
            float2 wv[4];
            float hv[4];
#pragma unroll
            for (int i = 0; i < 4; i++) pk[i] = epk[p + i];
#pragma unroll
            for (int i = 0; i < 4; i++) wv[i] = wz[p + i];
#pragma unroll
            for (int i = 0; i < 4; i++)
                hv[i] = (float)hin16[(size_t)(pk[i] & 0xFFFFu) * DD + lane];
#pragma unroll
            for (int i = 0; i < 4; i++) {
                int e = __builtin_amdgcn_readfirstlane((int)((pk[i] >> 16) & 15u));
                zacc += wv[i].x;
                AGG_EDGE(e, wv[i].y, hv[i]);
            }
        }
        for (; p < p1; ++p) {
            unsigned pk = epk[p];
            float2 wzv = wz[p];
            float hv = (float)hin16[(size_t)(pk & 0xFFFFu) * DD + lane];
            int e = __builtin_amdgcn_readfirstlane((int)((pk >> 16) & 15u));
            zacc += wzv.x;
            AGG_EDGE(e, wzv.y, hv);
        }
        float inv = 1.f / (zacc + 1e-16f);
#pragma unroll
        for (int r = 0; r < RR; r++) Ar[r * DD + lane] = (_Float16)(acc[r] * inv);
        Ar[768 + lane] = hin16[(size_t)node * DD + lane];   // self/skip cols
    }
    __syncthreads();

    // ---- phase 2: waves 0-3 compute col-tiles (16 cols each) ----
    if (w < 4) {
        const half8v* Bh8 = (const half8v*)Bh;
        const half8v* Bl8 = (const half8v*)Bl;
        const _Float16* abase = At + (lane & 15) * ASTR + ((lane >> 4) << 3);
        f32x4 acc0 = {0.f, 0.f, 0.f, 0.f};
#pragma unroll 4
        for (int ks = 0; ks < NKS; ++ks) {
            half8v ah = *(const half8v*)(abase + ks * 32);
            size_t bb = (size_t)(ks * 4 + w) * 64 + lane;
            half8v bh = Bh8[bb];
            half8v bl = Bl8[bb];
            acc0 = __builtin_amdgcn_mfma_f32_16x16x32_f16(ah, bh, acc0, 0, 0, 0);
            acc0 = __builtin_amdgcn_mfma_f32_16x16x32_f16(ah, bl, acc0, 0, 0, 0);
        }

        // epilogue: D layout col=lane&15, row=(lane>>4)*4+j
        int colb = lane & 15, kg = lane >> 4;
        int c = w * 16 + colb;
        float bv = bias[c];
#pragma unroll
        for (int j = 0; j < 4; j++) {
            int rl = kg * 4 + j;
            int row = nb0 + rl;
            if (row < N) {
                float v = acc0[j] + bv;
                if (act) v = v > 0.f ? v : 0.f;
                if (out) out[(size_t)row * DD + c] = v;
                if (hout16) hout16[(size_t)row * DD + c] = (_Float16)v;
                if (EWn) Hf[rl * 65 + c] = v;
            }
        }
    }

    // ---- EW epilogue: next layer's (ev, ev*gate) from the fp32 tile ----
    if (EWn) {
        __syncthreads();
        if (tid < TROWS * RR) {
            int nl = tid / RR, r = tid - nl * RR;
            int node = nb0 + nl;
            if (node < N) {
                const float* hp = Hf + nl * 65;
                const float* qp = qn + (size_t)r * DD;
                const float* gp = gn + (size_t)r * DD;
                float aq = 0.f, ag = 0.f;
#pragma unroll 8
                for (int cc = 0; cc < DD; cc++) {
                    float hv = hp[cc];
                    aq = fmaf(hv, qp[cc], aq);
                    ag = fmaf(hv, gp[cc], ag);
                }
                float sc = aq > 0.f ? aq : 0.01f * aq;
                float ev = expf(sc);
                float gate = 1.f / (1.f + expf(-(ag + gbn[0])));
                EWn[(size_t)node * RR + r] = make_float2(ev, ev * gate);
            }
        }
    }
}

extern "C" void kernel_launch(void* const* d_in, const int* in_sizes, int n_in,
                              void* d_out, int out_size, void* d_ws, size_t ws_size,
                              hipStream_t stream) {
    const float* x    = (const float*)d_in[0];
    const int*   src  = (const int*)d_in[1];
    const int*   dst  = (const int*)d_in[2];
    const int*   etyp = (const int*)d_in[3];
    const float* Wemb = (const float*)d_in[4];
    const float* bemb = (const float*)d_in[5];
    const int N = in_sizes[0];
    const int E = in_sizes[1];
    const int nbuck = (N + 127) >> 7;
    const int nblk2 = (E + EPB2 - 1) / EPB2;

    const float* Wrel[3];  const float* Wself[3]; const float* bb[3];
    const float* gwv[3];   const float* gbv[3];   const float* av[3];
    for (int l = 0; l < 3; l++) {
        int o = 6 + 6 * l;
        Wrel[l]  = (const float*)d_in[o + 0];
        Wself[l] = (const float*)d_in[o + 1];
        bb[l]    = (const float*)d_in[o + 2];
        gwv[l]   = (const float*)d_in[o + 3];
        gbv[l]   = (const float*)d_in[o + 4];
        av[l]    = (const float*)d_in[o + 5];
    }
    const float* Wskip[3] = { nullptr, (const float*)d_in[24], (const float*)d_in[25] };

    // ---- workspace ----
    float* p = (float*)d_ws;
    float* h0 = p; p += (size_t)N * DD;
    _Float16* h16A = (_Float16*)p; p += (size_t)N * DD / 2;   // fp16 copy (ping)
    _Float16* h16B = (_Float16*)p; p += (size_t)N * DD / 2;   // fp16 copy (pong)
    float2* EW = (float2*)p; p += (size_t)N * RR * 2;
    float* qv3[3]; float* gv3[3]; _Float16* Bh3[3]; _Float16* Bl3[3];
    for (int l = 0; l < 3; l++) {
        qv3[l] = p; p += RR * DD;
        gv3[l] = p; p += RR * DD;
        Bh3[l] = (_Float16*)p; p += NKS * 4 * 64 * 8 / 2;
        Bl3[l] = (_Float16*)p; p += NKS * 4 * 64 * 8 / 2;
    }
    unsigned* epk2 = (unsigned*)p; p += E;
    unsigned* epk  = (unsigned*)p; p += E;
    float2* wzv = (float2*)p; p += (size_t)E * 2;
    int* bcnt  = (int*)p; p += 512;
    int* bbase = (int*)p; p += 516;
    int* bcur  = (int*)p; p += 512;
    int* offd  = (int*)p; p += N + 4;

    const int B = 256;

    // weight prep for all 3 layers upfront (independent of h)
    for (int l = 0; l < 3; l++)
        k_wprep<<<NKS + 3, B, 0, stream>>>(Wrel[l], Wself[l], Wskip[l], av[l], gwv[l],
                                           Bh3[l], Bl3[l], qv3[l], gv3[l]);

    k_h0<<<(N * DD + B - 1) / B, B, 0, stream>>>(x, Wemb, bemb, h0, h16A, N);

    // coalesced two-level dst-sort (once; reused by all layers)
    hipMemsetAsync(bcnt, 0, 512 * 4, stream);
    k_bh<<<nblk2, 512, 0, stream>>>(dst, bcnt, E, nbuck);
    k_bscan<<<1, 512, 0, stream>>>(bcnt, bbase, bcur, nbuck, E);
    k_bscat<<<nblk2, 512, 0, stream>>>(src, dst, etyp, bcur, epk2, E, nbuck);
    k_b2<<<nbuck, 256, 0, stream>>>(epk2, bbase, epk, offd, N, E);

    // layer 1's EW from h0 (the only k_sgw launch)
    k_sgw<<<(N * RR + B - 1) / B, B, 0, stream>>>(h0, qv3[0], gv3[0], gbv[0], EW, N);

    const int fblocks = (N + TROWS - 1) / TROWS;
    const int eblocks = (E + B - 1) / B;

    // layer 1: in h16A, out h16B (no f32), EW for layer 2 computed in-epilogue
    k_ew<<<eblocks, B, 0, stream>>>(epk, EW, wzv, E);
    k_fused<<<fblocks, 512, 0, stream>>>(epk, offd, h16A, wzv, Bh3[0], Bl3[0],
                                         bb[0], nullptr, h16B, N, 1,
                                         qv3[1], gv3[1], gbv[1], EW);
    // layer 2: in h16B, out h16A (no f32), EW for layer 3 computed in-epilogue
    k_ew<<<eblocks, B, 0, stream>>>(epk, EW, wzv, E);
    k_fused<<<fblocks, 512, 0, stream>>>(epk, offd, h16B, wzv, Bh3[1], Bl3[1],
                                         bb[1], nullptr, h16A, N, 1,
                                         qv3[2], gv3[2], gbv[2], EW);
    // layer 3: in h16A, out d_out f32, no act, no EW
    k_ew<<<eblocks, B, 0, stream>>>(epk, EW, wzv, E);
    k_fused<<<fblocks, 512, 0, stream>>>(epk, offd, h16A, wzv, Bh3[2], Bl3[2],
                                         bb[2], (float*)d_out, nullptr, N, 0,
                                         nullptr, nullptr, nullptr, nullptr);
}

// Round 6
// 288.798 us; speedup vs baseline: 1.5838x; 1.1295x over previous
//
#include <hip/hip_runtime.h>

#define DD 64
#define RR 12
#define KTOT 832   // 768 (A·Wrel) + 64 (h·(Wself+Wskip))
#define NKS 26     // 832 / 32 k-steps
#define ASTR 840   // LDS A row stride in halfs (420 words ≡ 4 mod 32: even banks)
#define TROWS 16   // nodes per block tile — proven geometry, do not change
#define EPB2 8192  // edges per block in bucket passes

typedef _Float16 half8v __attribute__((ext_vector_type(8)));
typedef __attribute__((ext_vector_type(4))) float f32x4;

// ---------------- h0 = relu(x * W_emb + b_emb), x is [N,1]; also fp16 copy ----
__global__ void k_h0(const float* __restrict__ x, const float* __restrict__ Wemb,
                     const float* __restrict__ bemb, float* __restrict__ h0,
                     _Float16* __restrict__ h16, int N) {
    int idx = blockIdx.x * blockDim.x + threadIdx.x;
    if (idx >= N * DD) return;
    int n = idx >> 6, d = idx & 63;
    float v = x[n] * Wemb[d] + bemb[d];
    v = v > 0.f ? v : 0.f;
    h0[idx] = v;
    h16[idx] = (_Float16)v;
}

// EW[n*12+r] = (ev, ev*gate) — used only for layer 1 (from h0)
__global__ void k_sgw(const float* __restrict__ h, const float* __restrict__ q,
                      const float* __restrict__ g, const float* __restrict__ gb,
                      float2* __restrict__ EW, int N) {
    int t = blockIdx.x * blockDim.x + threadIdx.x;
    if (t >= N * RR) return;
    int n = t / RR, r = t - n * RR;
    const float4* hp = (const float4*)(h + (size_t)n * DD);
    const float4* qp = (const float4*)(q + (size_t)r * DD);
    const float4* gp = (const float4*)(g + (size_t)r * DD);
    float sq = 0.f, sg = 0.f;
#pragma unroll
    for (int k = 0; k < 16; k++) {
        float4 hv = hp[k], qv = qp[k], gv = gp[k];
        sq += hv.x * qv.x + hv.y * qv.y + hv.z * qv.z + hv.w * qv.w;
        sg += hv.x * gv.x + hv.y * gv.y + hv.z * gv.z + hv.w * gv.w;
    }
    float sc = sq > 0.f ? sq : 0.01f * sq;       // leaky_relu
    float ev = expf(sc);                          // softmax max-shift invariant
    float gate = 1.f / (1.f + expf(-(sg + gb[0])));
    EW[t] = make_float2(ev, ev * gate);
}

// ---- per-edge weight stream: wE = ev*gate, evv = ev (sorted-edge order) ----
__global__ void k_ew(const unsigned* __restrict__ epk, const float2* __restrict__ EW,
                     float* __restrict__ wE, float* __restrict__ evv, int E) {
    int t = blockIdx.x * blockDim.x + threadIdx.x;
    if (t >= E) return;
    unsigned pk = epk[t];
    int s = (int)(pk & 0xFFFFu);
    int e = (int)((pk >> 16) & 15u);
    float2 ew = EW[(size_t)s * RR + e];
    wE[t] = ew.y;
    evv[t] = ew.x;
}

// ---- per-node softmax denominator: Z[n] = sum evv over the node's range ----
__global__ void k_zn(const float* __restrict__ evv, const int* __restrict__ offd,
                     float* __restrict__ Z, int N) {
    int n = blockIdx.x * blockDim.x + threadIdx.x;
    if (n >= N) return;
    int a = offd[n], b = offd[n + 1];
    float z = 0.f;
    for (int p = a; p < b; ++p) z += evv[p];
    Z[n] = z;
}

// ============ coalesced two-level counting sort by dst ============
// bucket = dst >> 7 (128 nodes per bucket). payload u32 = dlow<<20 | et<<16 | src

__global__ void k_bh(const int* __restrict__ dst, int* __restrict__ bcnt,
                     int E, int nbuck) {
    __shared__ int lh[512];
    int tid = threadIdx.x;
    for (int i = tid; i < 512; i += 512) lh[i] = 0;
    __syncthreads();
    int base = blockIdx.x * EPB2;
    int lim = base + EPB2 < E ? base + EPB2 : E;
    for (int i = base + tid; i < lim; i += 512)
        atomicAdd(&lh[dst[i] >> 7], 1);
    __syncthreads();
    for (int i = tid; i < nbuck; i += 512)
        if (lh[i]) atomicAdd(&bcnt[i], lh[i]);
}

__global__ void k_bscan(const int* __restrict__ bcnt, int* __restrict__ bbase,
                        int* __restrict__ bcur, int nbuck, int E) {
    __shared__ int wsum[8];
    int tid = threadIdx.x, lane = tid & 63, wv = tid >> 6;
    int v = (tid < nbuck) ? bcnt[tid] : 0;
    int incl = v;
#pragma unroll
    for (int d = 1; d < 64; d <<= 1) {
        int t2 = __shfl_up(incl, d);
        if (lane >= d) incl += t2;
    }
    if (lane == 63) wsum[wv] = incl;
    __syncthreads();
    int pre = 0;
#pragma unroll
    for (int w = 0; w < 8; w++) if (w < wv) pre += wsum[w];
    int excl = pre + incl - v;
    if (tid < nbuck) { bbase[tid] = excl; bcur[tid] = excl; }
    if (tid == nbuck - 1) bbase[nbuck] = excl + v;   // == E
}

__global__ void k_bscat(const int* __restrict__ src, const int* __restrict__ dst,
                        const int* __restrict__ et, int* __restrict__ bcur,
                        unsigned* __restrict__ epk2, int E, int nbuck) {
    __shared__ int lh[512];
    __shared__ int lcur[512];
    int tid = threadIdx.x;
    for (int i = tid; i < 512; i += 512) lh[i] = 0;
    __syncthreads();
    int base = blockIdx.x * EPB2;
    int lim = base + EPB2 < E ? base + EPB2 : E;
    for (int i = base + tid; i < lim; i += 512)
        atomicAdd(&lh[dst[i] >> 7], 1);
    __syncthreads();
    for (int i = tid; i < nbuck; i += 512)
        lcur[i] = lh[i] ? atomicAdd(&bcur[i], lh[i]) : 0;
    __syncthreads();
    for (int i = base + tid; i < lim; i += 512) {
        int d = dst[i];
        int pos = atomicAdd(&lcur[d >> 7], 1);
        epk2[pos] = ((unsigned)(d & 127) << 20) | ((unsigned)et[i] << 16) | (unsigned)src[i];
    }
}

__global__ void k_b2(const unsigned* __restrict__ epk2, const int* __restrict__ bbase,
                     unsigned* __restrict__ epk, int* __restrict__ offd,
                     int N, int E) {
    int b = blockIdx.x, tid = threadIdx.x;
    int p0 = bbase[b], p1 = bbase[b + 1], cb = p1 - p0;
    __shared__ int hist[128], cur[128];
    __shared__ unsigned stg[4096];
    if (tid < 128) hist[tid] = 0;
    __syncthreads();
    for (int i = tid; i < cb; i += 256)
        atomicAdd(&hist[(epk2[p0 + i] >> 20) & 127], 1);
    __syncthreads();
    if (tid == 0) {
        int a = 0;
        for (int j = 0; j < 128; j++) { int c = hist[j]; hist[j] = a; a += c; }
    }
    __syncthreads();
    if (tid < 128) {
        cur[tid] = hist[tid];
        int node = b * 128 + tid;
        if (node < N) offd[node] = p0 + hist[tid];
    }
    if (b == 0 && tid == 0) offd[N] = E;
    __syncthreads();
    if (cb <= 4096) {
        for (int i = tid; i < cb; i += 256) {
            unsigned pk = epk2[p0 + i];
            int pos = atomicAdd(&cur[(pk >> 20) & 127], 1);
            stg[pos] = pk & 0xFFFFFu;
        }
        __syncthreads();
        for (int i = tid; i < cb; i += 256) epk[p0 + i] = stg[i];
    } else {   // statistically never; correctness fallback
        for (int i = tid; i < cb; i += 256) {
            unsigned pk = epk2[p0 + i];
            int pos = atomicAdd(&cur[(pk >> 20) & 127], 1);
            epk[p0 + pos] = pk & 0xFFFFFu;
        }
    }
}

// -------- weight prep: blocks 0..25 = B fragments (fp16 hi/lo planes);
//          blocks 26..28 = q/g projection vectors --------
__global__ void k_wprep(const float* __restrict__ Wrel, const float* __restrict__ Wself,
                        const float* __restrict__ Wskip, const float* __restrict__ av,
                        const float* __restrict__ gw,
                        _Float16* __restrict__ Bh, _Float16* __restrict__ Bl,
                        float* __restrict__ q, float* __restrict__ g) {
    int bx = blockIdx.x;
    if (bx < NKS) {
        int t = bx * 256 + threadIdx.x;
        int ks = t >> 8, ct = (t >> 6) & 3, lane = t & 63;
        int col = ct * 16 + (lane & 15);
        int kb = ks * 32 + ((lane >> 4) << 3);
        _Float16* ph = Bh + (size_t)t * 8;
        _Float16* pl = Bl + (size_t)t * 8;
#pragma unroll
        for (int i = 0; i < 8; i++) {
            int k = kb + i;
            float v;
            if (k < 768) v = Wrel[(size_t)k * DD + col];
            else {
                v = Wself[(size_t)(k - 768) * DD + col];
                if (Wskip) v += Wskip[(size_t)(k - 768) * DD + col];
            }
            _Float16 h = (_Float16)v;
            ph[i] = h;
            pl[i] = (_Float16)(v - (float)h);
        }
    } else {
        int t = (bx - NKS) * 256 + threadIdx.x;
        if (t >= RR * DD) return;
        const float* wp = Wrel + (size_t)t * DD;
        float aq = 0.f, ag = 0.f;
#pragma unroll
        for (int e = 0; e < DD; e++) { float w = wp[e]; aq += w * av[e]; ag += w * gw[e]; }
        q[t] = aq; g[t] = ag;
    }
}

// ---------------- fused layer kernel: aggregate -> LDS A-tile -> MFMA ------
// Phase 1: batched deep-MLP gathers. Raw _Float16 hr[NB] loads (1 VGPR each,
// cvt deferred to the process loop), scalar pk/wE path, sched_barrier(0)
// between issue and process so the compiler cannot interleave gathers with
// the switch region (the round-2/round-5 re-roll: VGPR_Count 28 = ~4 in
// flight). Batches {16,8,4,2,1}.
#define AGG_EDGE(ee, wy, hh)                                       \
    switch (ee) {                                                  \
        case 0:  acc[0]  = fmaf(wy, hh, acc[0]);  break;           \
        case 1:  acc[1]  = fmaf(wy, hh, acc[1]);  break;           \
        case 2:  acc[2]  = fmaf(wy, hh, acc[2]);  break;           \
        case 3:  acc[3]  = fmaf(wy, hh, acc[3]);  break;           \
        case 4:  acc[4]  = fmaf(wy, hh, acc[4]);  break;           \
        case 5:  acc[5]  = fmaf(wy, hh, acc[5]);  break;           \
        case 6:  acc[6]  = fmaf(wy, hh, acc[6]);  break;           \
        case 7:  acc[7]  = fmaf(wy, hh, acc[7]);  break;           \
        case 8:  acc[8]  = fmaf(wy, hh, acc[8]);  break;           \
        case 9:  acc[9]  = fmaf(wy, hh, acc[9]);  break;           \
        case 10: acc[10] = fmaf(wy, hh, acc[10]); break;           \
        default: acc[11] = fmaf(wy, hh, acc[11]); break;           \
    }

template<int NB>
__device__ __forceinline__ void ebatch(const unsigned* __restrict__ epk,
                                       const float* __restrict__ wE,
                                       const _Float16* __restrict__ hin16,
                                       int p, int lane, float acc[RR]) {
    unsigned pk[NB];
    float wv[NB];
    _Float16 hr[NB];
#pragma unroll
    for (int i = 0; i < NB; i++) pk[i] = epk[p + i];
#pragma unroll
    for (int i = 0; i < NB; i++) hr[i] = hin16[(size_t)(pk[i] & 0xFFFFu) * DD + lane];
#pragma unroll
    for (int i = 0; i < NB; i++) wv[i] = wE[p + i];
    __builtin_amdgcn_sched_barrier(0);
#pragma unroll
    for (int i = 0; i < NB; i++) {
        int e = __builtin_amdgcn_readfirstlane((int)((pk[i] >> 16) & 15u));
        float hh = (float)hr[i];
        AGG_EDGE(e, wv[i], hh);
    }
}

__global__ void __launch_bounds__(512, 8)
k_fused(const unsigned* __restrict__ epk, const int* __restrict__ offd,
        const _Float16* __restrict__ hin16, const float* __restrict__ wE,
        const float* __restrict__ Z,
        const _Float16* __restrict__ Bh, const _Float16* __restrict__ Bl,
        const float* __restrict__ bias, float* __restrict__ out,
        _Float16* __restrict__ hout16, int N, int act,
        const float* __restrict__ qn, const float* __restrict__ gn,
        const float* __restrict__ gbn, float2* __restrict__ EWn) {
    __shared__ __align__(16) _Float16 At[TROWS * ASTR];   // 26880 B
    __shared__ __align__(16) float Hf[TROWS * 68];        //  4352 B (stride 68: aligned, ≤2-way banks)
    __shared__ __align__(16) float qg[2 * RR * 68];       //  6528 B
    __shared__ int offs[TROWS + 1];
    __shared__ int claim;
    int tid = threadIdx.x, lane = tid & 63, w = tid >> 6;
    int nb0 = blockIdx.x * TROWS;
    if (tid == 0) claim = 0;
    if (tid < TROWS + 1) {
        int nn = nb0 + tid;
        offs[tid] = (nn <= N) ? offd[nn] : 0;
    }
    if (EWn) {   // preload next layer's q/g into LDS (stride 68)
        for (int i = tid; i < RR * DD; i += 512) {
            int r = i >> 6, c = i & 63;
            qg[r * 68 + c] = qn[i];
            qg[816 + r * 68 + c] = gn[i];
        }
    }
    __syncthreads();

    // ---- phase 1: waves claim nodes until the tile is done ----
    for (;;) {
        int t0 = 0;
        if (lane == 0) t0 = atomicAdd(&claim, 1);
        int nl = __builtin_amdgcn_readfirstlane(t0);
        if (nl >= TROWS) break;
        int node = nb0 + nl;
        _Float16* Ar = At + nl * ASTR;
        if (node >= N) {
            for (int k = lane; k < KTOT; k += 64) Ar[k] = (_Float16)0.f;
            continue;
        }
        int p0 = __builtin_amdgcn_readfirstlane(offs[nl]);
        int p1 = __builtin_amdgcn_readfirstlane(offs[nl + 1]);
        float acc[RR];
#pragma unroll
        for (int r = 0; r < RR; r++) acc[r] = 0.f;
        int p = p0;
        while (p + 16 <= p1) { ebatch<16>(epk, wE, hin16, p, lane, acc); p += 16; }
        if (p + 8 <= p1) { ebatch<8>(epk, wE, hin16, p, lane, acc); p += 8; }
        if (p + 4 <= p1) { ebatch<4>(epk, wE, hin16, p, lane, acc); p += 4; }
        if (p + 2 <= p1) { ebatch<2>(epk, wE, hin16, p, lane, acc); p += 2; }
        if (p < p1)      { ebatch<1>(epk, wE, hin16, p, lane, acc); }
        float inv = 1.f / (Z[node] + 1e-16f);
#pragma unroll
        for (int r = 0; r < RR; r++) Ar[r * DD + lane] = (_Float16)(acc[r] * inv);
        Ar[768 + lane] = hin16[(size_t)node * DD + lane];   // self/skip cols
    }
    __syncthreads();

    // ---- phase 2: waves 0-3 compute col-tiles (16 cols each) ----
    if (w < 4) {
        const half8v* Bh8 = (const half8v*)Bh;
        const half8v* Bl8 = (const half8v*)Bl;
        const _Float16* abase = At + (lane & 15) * ASTR + ((lane >> 4) << 3);
        f32x4 acc0 = {0.f, 0.f, 0.f, 0.f};
#pragma unroll 4
        for (int ks = 0; ks < NKS; ++ks) {
            half8v ah = *(const half8v*)(abase + ks * 32);
            size_t bb = (size_t)(ks * 4 + w) * 64 + lane;
            half8v bh = Bh8[bb];
            half8v bl = Bl8[bb];
            acc0 = __builtin_amdgcn_mfma_f32_16x16x32_f16(ah, bh, acc0, 0, 0, 0);
            acc0 = __builtin_amdgcn_mfma_f32_16x16x32_f16(ah, bl, acc0, 0, 0, 0);
        }

        // epilogue: D layout col=lane&15, row=(lane>>4)*4+j
        int colb = lane & 15, kg = lane >> 4;
        int c = w * 16 + colb;
        float bv = bias[c];
#pragma unroll
        for (int j = 0; j < 4; j++) {
            int rl = kg * 4 + j;
            int row = nb0 + rl;
            if (row < N) {
                float v = acc0[j] + bv;
                if (act) v = v > 0.f ? v : 0.f;
                if (out) out[(size_t)row * DD + c] = v;
                if (hout16) hout16[(size_t)row * DD + c] = (_Float16)v;
                if (EWn) Hf[rl * 68 + c] = v;
            }
        }
    }

    // ---- EW epilogue: next layer's (ev, ev*gate) from fp32 tile, all-LDS ----
    if (EWn) {
        __syncthreads();
        if (tid < TROWS * RR) {
            int nl = tid / RR, r = tid - nl * RR;
            int node = nb0 + nl;
            if (node < N) {
                const float* hp = Hf + nl * 68;
                const float* qp = qg + r * 68;
                const float* gp = qg + 816 + r * 68;
                float aq = 0.f, ag = 0.f;
#pragma unroll
                for (int c4 = 0; c4 < 16; c4++) {
                    float4 hv = *(const float4*)(hp + c4 * 4);
                    float4 qv = *(const float4*)(qp + c4 * 4);
                    float4 gv = *(const float4*)(gp + c4 * 4);
                    aq += hv.x * qv.x + hv.y * qv.y + hv.z * qv.z + hv.w * qv.w;
                    ag += hv.x * gv.x + hv.y * gv.y + hv.z * gv.z + hv.w * gv.w;
                }
                float sc = aq > 0.f ? aq : 0.01f * aq;
                float ev = expf(sc);
                float gate = 1.f / (1.f + expf(-(ag + gbn[0])));
                EWn[(size_t)node * RR + r] = make_float2(ev, ev * gate);
            }
        }
    }
}

extern "C" void kernel_launch(void* const* d_in, const int* in_sizes, int n_in,
                              void* d_out, int out_size, void* d_ws, size_t ws_size,
                              hipStream_t stream) {
    const float* x    = (const float*)d_in[0];
    const int*   src  = (const int*)d_in[1];
    const int*   dst  = (const int*)d_in[2];
    const int*   etyp = (const int*)d_in[3];
    const float* Wemb = (const float*)d_in[4];
    const float* bemb = (const float*)d_in[5];
    const int N = in_sizes[0];
    const int E = in_sizes[1];
    const int nbuck = (N + 127) >> 7;
    const int nblk2 = (E + EPB2 - 1) / EPB2;

    const float* Wrel[3];  const float* Wself[3]; const float* bb[3];
    const float* gwv[3];   const float* gbv[3];   const float* av[3];
    for (int l = 0; l < 3; l++) {
        int o = 6 + 6 * l;
        Wrel[l]  = (const float*)d_in[o + 0];
        Wself[l] = (const float*)d_in[o + 1];
        bb[l]    = (const float*)d_in[o + 2];
        gwv[l]   = (const float*)d_in[o + 3];
        gbv[l]   = (const float*)d_in[o + 4];
        av[l]    = (const float*)d_in[o + 5];
    }
    const float* Wskip[3] = { nullptr, (const float*)d_in[24], (const float*)d_in[25] };

    // ---- workspace ----
    float* p = (float*)d_ws;
    float* h0 = p; p += (size_t)N * DD;
    _Float16* h16A = (_Float16*)p; p += (size_t)N * DD / 2;   // fp16 copy (ping)
    _Float16* h16B = (_Float16*)p; p += (size_t)N * DD / 2;   // fp16 copy (pong)
    float2* EW = (float2*)p; p += (size_t)N * RR * 2;
    float* qv3[3]; float* gv3[3]; _Float16* Bh3[3]; _Float16* Bl3[3];
    for (int l = 0; l < 3; l++) {
        qv3[l] = p; p += RR * DD;
        gv3[l] = p; p += RR * DD;
        Bh3[l] = (_Float16*)p; p += NKS * 4 * 64 * 8 / 2;
        Bl3[l] = (_Float16*)p; p += NKS * 4 * 64 * 8 / 2;
    }
    unsigned* epk2 = (unsigned*)p; p += E;
    unsigned* epk  = (unsigned*)p; p += E;
    float* wEv = p; p += E;
    float* evv = p; p += E;
    float* Z   = p; p += N;
    int* bcnt  = (int*)p; p += 512;
    int* bbase = (int*)p; p += 516;
    int* bcur  = (int*)p; p += 512;
    int* offd  = (int*)p; p += N + 4;

    const int B = 256;

    // weight prep for all 3 layers upfront (independent of h)
    for (int l = 0; l < 3; l++)
        k_wprep<<<NKS + 3, B, 0, stream>>>(Wrel[l], Wself[l], Wskip[l], av[l], gwv[l],
                                           Bh3[l], Bl3[l], qv3[l], gv3[l]);

    k_h0<<<(N * DD + B - 1) / B, B, 0, stream>>>(x, Wemb, bemb, h0, h16A, N);

    // coalesced two-level dst-sort (once; reused by all layers)
    hipMemsetAsync(bcnt, 0, 512 * 4, stream);
    k_bh<<<nblk2, 512, 0, stream>>>(dst, bcnt, E, nbuck);
    k_bscan<<<1, 512, 0, stream>>>(bcnt, bbase, bcur, nbuck, E);
    k_bscat<<<nblk2, 512, 0, stream>>>(src, dst, etyp, bcur, epk2, E, nbuck);
    k_b2<<<nbuck, 256, 0, stream>>>(epk2, bbase, epk, offd, N, E);

    // layer 1's EW from h0 (the only k_sgw launch)
    k_sgw<<<(N * RR + B - 1) / B, B, 0, stream>>>(h0, qv3[0], gv3[0], gbv[0], EW, N);

    const int fblocks = (N + TROWS - 1) / TROWS;
    const int eblocks = (E + B - 1) / B;
    const int nblocks = (N + B - 1) / B;

    // layer 1: in h16A, out h16B; EW for layer 2 computed in-epilogue
    k_ew<<<eblocks, B, 0, stream>>>(epk, EW, wEv, evv, E);
    k_zn<<<nblocks, B, 0, stream>>>(evv, offd, Z, N);
    k_fused<<<fblocks, 512, 0, stream>>>(epk, offd, h16A, wEv, Z, Bh3[0], Bl3[0],
                                         bb[0], nullptr, h16B, N, 1,
                                         qv3[1], gv3[1], gbv[1], EW);
    // layer 2: in h16B, out h16A; EW for layer 3 computed in-epilogue
    k_ew<<<eblocks, B, 0, stream>>>(epk, EW, wEv, evv, E);
    k_zn<<<nblocks, B, 0, stream>>>(evv, offd, Z, N);
    k_fused<<<fblocks, 512, 0, stream>>>(epk, offd, h16B, wEv, Z, Bh3[1], Bl3[1],
                                         bb[1], nullptr, h16A, N, 1,
                                         qv3[2], gv3[2], gbv[2], EW);
    // layer 3: in h16A, out d_out f32, no act, no EW
    k_ew<<<eblocks, B, 0, stream>>>(epk, EW, wEv, evv, E);
    k_zn<<<nblocks, B, 0, stream>>>(evv, offd, Z, N);
    k_fused<<<fblocks, 512, 0, stream>>>(epk, offd, h16A, wEv, Z, Bh3[2], Bl3[2],
                                         bb[2], (float*)d_out, nullptr, N, 0,
                                         nullptr, nullptr, nullptr, nullptr);
}

// Round 7
// 255.966 us; speedup vs baseline: 1.7869x; 1.1283x over previous
//
#include <hip/hip_runtime.h>

#define DD 64
#define RR 12
#define KTOT 832   // 768 (A·Wrel) + 64 (h·(Wself+Wskip))
#define NKS 26     // 832 / 32 k-steps
#define ASTR 840   // LDS A row stride in halfs (420 words ≡ 4 mod 32: even banks)
#define TROWS 16   // nodes per block tile — proven geometry, do not change
#define EPB2 8192  // edges per block in bucket passes

typedef _Float16 half8v __attribute__((ext_vector_type(8)));
typedef __attribute__((ext_vector_type(4))) float f32x4;

// ---------------- h16 = fp16(relu(x * W_emb + b_emb)), x is [N,1] ----
__global__ void k_h0(const float* __restrict__ x, const float* __restrict__ Wemb,
                     const float* __restrict__ bemb, _Float16* __restrict__ h16, int N) {
    int idx = blockIdx.x * blockDim.x + threadIdx.x;
    if (idx >= N * DD) return;
    int n = idx >> 6, d = idx & 63;
    float v = fmaf(x[n], Wemb[d], bemb[d]);
    v = v > 0.f ? v : 0.f;
    h16[idx] = (_Float16)v;
}

// layer-1 EW table straight from x (h0 row is a function of scalar x[n]):
// EW[n*12+r] = (ev, ev*gate)
__global__ void k_sgw2(const float* __restrict__ x, const float* __restrict__ Wemb,
                       const float* __restrict__ bemb,
                       const float* __restrict__ q, const float* __restrict__ g,
                       const float* __restrict__ gb, float2* __restrict__ EW, int N) {
    __shared__ float We[DD], Be[DD], qs[RR * 65], gs[RR * 65];
    int tid = threadIdx.x;
    if (tid < DD) { We[tid] = Wemb[tid]; Be[tid] = bemb[tid]; }
    for (int i = tid; i < RR * DD; i += 256) {
        int r = i >> 6, c = i & 63;
        qs[r * 65 + c] = q[i];
        gs[r * 65 + c] = g[i];
    }
    __syncthreads();
    int t = blockIdx.x * 256 + tid;
    if (t >= N * RR) return;
    int n = t / RR, r = t - n * RR;
    float xv = x[n];
    const float* qp = qs + r * 65;
    const float* gp = gs + r * 65;
    float aq = 0.f, ag = 0.f;
#pragma unroll
    for (int d = 0; d < DD; d++) {
        float h = fmaf(xv, We[d], Be[d]);
        h = h > 0.f ? h : 0.f;
        aq = fmaf(h, qp[d], aq);
        ag = fmaf(h, gp[d], ag);
    }
    float sc = aq > 0.f ? aq : 0.01f * aq;       // leaky_relu
    float ev = expf(sc);                          // softmax max-shift invariant
    float gate = 1.f / (1.f + expf(-(ag + gb[0])));
    EW[t] = make_float2(ev, ev * gate);
}

// ---- per-edge weight stream in sorted order: wE[p] = ev*gate ----
__global__ void k_ew(const unsigned* __restrict__ epk, const float2* __restrict__ EW,
                     float* __restrict__ wE, int E) {
    int t = blockIdx.x * blockDim.x + threadIdx.x;
    if (t >= E) return;
    unsigned pk = epk[t];
    int s = (int)(pk & 0xFFFFu);
    int e = (int)((pk >> 16) & 15u);
    wE[t] = EW[(size_t)s * RR + e].y;
}

// ============ coalesced two-level counting sort by dst ============
// bucket = dst >> 7 (128 nodes per bucket). payload u32 = dlow<<20 | et<<16 | src

__global__ void k_bh(const int* __restrict__ dst, int* __restrict__ bcnt,
                     int E, int nbuck) {
    __shared__ int lh[512];
    int tid = threadIdx.x;
    for (int i = tid; i < 512; i += 512) lh[i] = 0;
    __syncthreads();
    int base = blockIdx.x * EPB2;
    int lim = base + EPB2 < E ? base + EPB2 : E;
    for (int i = base + tid; i < lim; i += 512)
        atomicAdd(&lh[dst[i] >> 7], 1);
    __syncthreads();
    for (int i = tid; i < nbuck; i += 512)
        if (lh[i]) atomicAdd(&bcnt[i], lh[i]);
}

__global__ void k_bscan(const int* __restrict__ bcnt, int* __restrict__ bbase,
                        int* __restrict__ bcur, int nbuck, int E) {
    __shared__ int wsum[8];
    int tid = threadIdx.x, lane = tid & 63, wv = tid >> 6;
    int v = (tid < nbuck) ? bcnt[tid] : 0;
    int incl = v;
#pragma unroll
    for (int d = 1; d < 64; d <<= 1) {
        int t2 = __shfl_up(incl, d);
        if (lane >= d) incl += t2;
    }
    if (lane == 63) wsum[wv] = incl;
    __syncthreads();
    int pre = 0;
#pragma unroll
    for (int w = 0; w < 8; w++) if (w < wv) pre += wsum[w];
    int excl = pre + incl - v;
    if (tid < nbuck) { bbase[tid] = excl; bcur[tid] = excl; }
    if (tid == nbuck - 1) bbase[nbuck] = excl + v;   // == E
}

__global__ void k_bscat(const int* __restrict__ src, const int* __restrict__ dst,
                        const int* __restrict__ et, int* __restrict__ bcur,
                        unsigned* __restrict__ epk2, int E, int nbuck) {
    __shared__ int lh[512];
    __shared__ int lcur[512];
    int tid = threadIdx.x;
    for (int i = tid; i < 512; i += 512) lh[i] = 0;
    __syncthreads();
    int base = blockIdx.x * EPB2;
    int lim = base + EPB2 < E ? base + EPB2 : E;
    for (int i = base + tid; i < lim; i += 512)
        atomicAdd(&lh[dst[i] >> 7], 1);
    __syncthreads();
    for (int i = tid; i < nbuck; i += 512)
        lcur[i] = lh[i] ? atomicAdd(&bcur[i], lh[i]) : 0;
    __syncthreads();
    for (int i = base + tid; i < lim; i += 512) {
        int d = dst[i];
        int pos = atomicAdd(&lcur[d >> 7], 1);
        epk2[pos] = ((unsigned)(d & 127) << 20) | ((unsigned)et[i] << 16) | (unsigned)src[i];
    }
}

// second pass: sort by 11-bit (dlow, et) key; emit offd (per node) and
// cnt16[node*12+et] (per-type in-degree, for the in-kernel Z).
__global__ void k_b2(const unsigned* __restrict__ epk2, const int* __restrict__ bbase,
                     unsigned* __restrict__ epk, int* __restrict__ offd,
                     unsigned short* __restrict__ cnt16, int N, int E) {
    int b = blockIdx.x, tid = threadIdx.x;
    int p0 = bbase[b], p1 = bbase[b + 1], cb = p1 - p0;
    __shared__ int hist[1536];      // counts → within-node exclusive prefix
    __shared__ int cur[1536];
    __shared__ int nodeTot[128], nodeExcl[128];
    __shared__ int wsum1;
    __shared__ unsigned stg[4096];
    for (int i = tid; i < 1536; i += 256) hist[i] = 0;
    __syncthreads();
    for (int i = tid; i < cb; i += 256) {
        unsigned pk = epk2[p0 + i];
        int key = (int)((pk >> 20) & 127u) * 12 + (int)((pk >> 16) & 15u);
        atomicAdd(&hist[key], 1);
    }
    __syncthreads();
    int incl = 0, v = 0;
    if (tid < 128) {
        int base = tid * 12, s = 0;
#pragma unroll
        for (int j = 0; j < 12; j++) { int c = hist[base + j]; hist[base + j] = s; s += c; }
        nodeTot[tid] = s;
        v = s; incl = s;
        int lane = tid & 63;
#pragma unroll
        for (int d = 1; d < 64; d <<= 1) {
            int t2 = __shfl_up(incl, d);
            if (lane >= d) incl += t2;
        }
        if (tid == 63) wsum1 = incl;
    }
    __syncthreads();
    if (tid < 128) {
        int pre = (tid >= 64) ? wsum1 : 0;
        nodeExcl[tid] = pre + incl - v;
    }
    __syncthreads();
    if (tid < 128) {
        int node = b * 128 + tid;
        int base = tid * 12;
        if (node < N) {
            offd[node] = p0 + nodeExcl[tid];
#pragma unroll
            for (int j = 0; j < 12; j++) {
                int c = ((j < 11) ? hist[base + j + 1] : nodeTot[tid]) - hist[base + j];
                cnt16[(size_t)node * 12 + j] = (unsigned short)c;
            }
        }
#pragma unroll
        for (int j = 0; j < 12; j++) cur[base + j] = nodeExcl[tid] + hist[base + j];
    }
    if (b == 0 && tid == 0) offd[N] = E;
    __syncthreads();
    if (cb <= 4096) {
        for (int i = tid; i < cb; i += 256) {
            unsigned pk = epk2[p0 + i];
            int key = (int)((pk >> 20) & 127u) * 12 + (int)((pk >> 16) & 15u);
            int pos = atomicAdd(&cur[key], 1);
            stg[pos] = pk & 0xFFFFFu;
        }
        __syncthreads();
        for (int i = tid; i < cb; i += 256) epk[p0 + i] = stg[i];
    } else {   // statistically never; correctness fallback
        for (int i = tid; i < cb; i += 256) {
            unsigned pk = epk2[p0 + i];
            int key = (int)((pk >> 20) & 127u) * 12 + (int)((pk >> 16) & 15u);
            int pos = atomicAdd(&cur[key], 1);
            epk[p0 + pos] = pk & 0xFFFFFu;
        }
    }
}

// -------- weight prep: blocks 0..25 = B fragments (fp16 hi/lo planes);
//          blocks 26..28 = q/g projection vectors --------
__global__ void k_wprep(const float* __restrict__ Wrel, const float* __restrict__ Wself,
                        const float* __restrict__ Wskip, const float* __restrict__ av,
                        const float* __restrict__ gw,
                        _Float16* __restrict__ Bh, _Float16* __restrict__ Bl,
                        float* __restrict__ q, float* __restrict__ g) {
    int bx = blockIdx.x;
    if (bx < NKS) {
        int t = bx * 256 + threadIdx.x;
        int ks = t >> 8, ct = (t >> 6) & 3, lane = t & 63;
        int col = ct * 16 + (lane & 15);
        int kb = ks * 32 + ((lane >> 4) << 3);
        _Float16* ph = Bh + (size_t)t * 8;
        _Float16* pl = Bl + (size_t)t * 8;
#pragma unroll
        for (int i = 0; i < 8; i++) {
            int k = kb + i;
            float v;
            if (k < 768) v = Wrel[(size_t)k * DD + col];
            else {
                v = Wself[(size_t)(k - 768) * DD + col];
                if (Wskip) v += Wskip[(size_t)(k - 768) * DD + col];
            }
            _Float16 h = (_Float16)v;
            ph[i] = h;
            pl[i] = (_Float16)(v - (float)h);
        }
    } else {
        int t = (bx - NKS) * 256 + threadIdx.x;
        if (t >= RR * DD) return;
        const float* wp = Wrel + (size_t)t * DD;
        float aq = 0.f, ag = 0.f;
#pragma unroll
        for (int e = 0; e < DD; e++) { float w = wp[e]; aq += w * av[e]; ag += w * gw[e]; }
        q[t] = aq; g[t] = ag;
    }
}

// ---------------- fused layer kernel: aggregate -> LDS A-tile -> MFMA ------
// Phase 1: batched deep-MLP gathers (16 raw-f16 loads in flight, pk/wE on the
// scalar path). inv computed UP FRONT from the node's own EW row × per-type
// counts (one coalesced 96B read + shuffle reduce) — no Z array, no k_zn.
#define AGG_EDGE(ee, wy, hh)                                       \
    switch (ee) {                                                  \
        case 0:  acc[0]  = fmaf(wy, hh, acc[0]);  break;           \
        case 1:  acc[1]  = fmaf(wy, hh, acc[1]);  break;           \
        case 2:  acc[2]  = fmaf(wy, hh, acc[2]);  break;           \
        case 3:  acc[3]  = fmaf(wy, hh, acc[3]);  break;           \
        case 4:  acc[4]  = fmaf(wy, hh, acc[4]);  break;           \
        case 5:  acc[5]  = fmaf(wy, hh, acc[5]);  break;           \
        case 6:  acc[6]  = fmaf(wy, hh, acc[6]);  break;           \
        case 7:  acc[7]  = fmaf(wy, hh, acc[7]);  break;           \
        case 8:  acc[8]  = fmaf(wy, hh, acc[8]);  break;           \
        case 9:  acc[9]  = fmaf(wy, hh, acc[9]);  break;           \
        case 10: acc[10] = fmaf(wy, hh, acc[10]); break;           \
        default: acc[11] = fmaf(wy, hh, acc[11]); break;           \
    }

template<int NB>
__device__ __forceinline__ void ebatch(const unsigned* __restrict__ epk,
                                       const float* __restrict__ wE,
                                       const _Float16* __restrict__ hin16,
                                       int p, int lane, float acc[RR]) {
    unsigned pk[NB];
    float wv[NB];
    _Float16 hr[NB];
#pragma unroll
    for (int i = 0; i < NB; i++) pk[i] = epk[p + i];
#pragma unroll
    for (int i = 0; i < NB; i++) hr[i] = hin16[(size_t)(pk[i] & 0xFFFFu) * DD + lane];
#pragma unroll
    for (int i = 0; i < NB; i++) wv[i] = wE[p + i];
    __builtin_amdgcn_sched_barrier(0);
#pragma unroll
    for (int i = 0; i < NB; i++) {
        int e = __builtin_amdgcn_readfirstlane((int)((pk[i] >> 16) & 15u));
        float hh = (float)hr[i];
        AGG_EDGE(e, wv[i], hh);
    }
}

__global__ void __launch_bounds__(512, 8)
k_fused(const unsigned* __restrict__ epk, const int* __restrict__ offd,
        const _Float16* __restrict__ hin16, const float* __restrict__ wE,
        float2* EWtab, const unsigned short* __restrict__ cnt16,
        const _Float16* __restrict__ Bh, const _Float16* __restrict__ Bl,
        const float* __restrict__ bias, float* __restrict__ out,
        _Float16* __restrict__ hout16, int N, int act, int doEWn,
        const float* __restrict__ qn, const float* __restrict__ gn,
        const float* __restrict__ gbn) {
    __shared__ __align__(16) _Float16 At[TROWS * ASTR];   // 26880 B
    __shared__ __align__(16) float Hf[TROWS * 68];        //  4352 B
    __shared__ __align__(16) float qg[2 * RR * 68];       //  6528 B
    __shared__ int offs[TROWS + 1];
    __shared__ int claim;
    int tid = threadIdx.x, lane = tid & 63, w = tid >> 6;
    int nb0 = blockIdx.x * TROWS;
    if (tid == 0) claim = 0;
    if (tid < TROWS + 1) {
        int nn = nb0 + tid;
        offs[tid] = (nn <= N) ? offd[nn] : 0;
    }
    if (doEWn) {   // preload next layer's q/g into LDS (stride 68)
        for (int i = tid; i < RR * DD; i += 512) {
            int r = i >> 6, c = i & 63;
            qg[r * 68 + c] = qn[i];
            qg[816 + r * 68 + c] = gn[i];
        }
    }
    __syncthreads();

    // ---- phase 1: waves claim nodes until the tile is done ----
    for (;;) {
        int t0 = 0;
        if (lane == 0) t0 = atomicAdd(&claim, 1);
        int nl = __builtin_amdgcn_readfirstlane(t0);
        if (nl >= TROWS) break;
        int node = nb0 + nl;
        _Float16* Ar = At + nl * ASTR;
        if (node >= N) {
            for (int k = lane; k < KTOT; k += 64) Ar[k] = (_Float16)0.f;
            continue;
        }
        int p0 = __builtin_amdgcn_readfirstlane(offs[nl]);
        int p1 = __builtin_amdgcn_readfirstlane(offs[nl + 1]);

        // Z from the node's own EW row × per-type in-degree (issued before
        // the edge loop; latency hides under the first pk scalar loads)
        float zl = 0.f;
        if (lane < RR) {
            float2 ewv = EWtab[(size_t)node * RR + lane];
            zl = ewv.x * (float)cnt16[(size_t)node * RR + lane];
        }
#pragma unroll
        for (int off = 32; off > 0; off >>= 1) zl += __shfl_xor(zl, off);
        float inv = 1.f / (zl + 1e-16f);

        float acc[RR];
#pragma unroll
        for (int r = 0; r < RR; r++) acc[r] = 0.f;
        int p = p0;
        while (p + 16 <= p1) { ebatch<16>(epk, wE, hin16, p, lane, acc); p += 16; }
        if (p + 8 <= p1) { ebatch<8>(epk, wE, hin16, p, lane, acc); p += 8; }
        if (p + 4 <= p1) { ebatch<4>(epk, wE, hin16, p, lane, acc); p += 4; }
        if (p + 2 <= p1) { ebatch<2>(epk, wE, hin16, p, lane, acc); p += 2; }
        if (p < p1)      { ebatch<1>(epk, wE, hin16, p, lane, acc); }
#pragma unroll
        for (int r = 0; r < RR; r++) Ar[r * DD + lane] = (_Float16)(acc[r] * inv);
        Ar[768 + lane] = hin16[(size_t)node * DD + lane];   // self/skip cols
    }
    __syncthreads();

    // ---- phase 2: waves 0-3 compute col-tiles (16 cols each) ----
    if (w < 4) {
        const half8v* Bh8 = (const half8v*)Bh;
        const half8v* Bl8 = (const half8v*)Bl;
        const _Float16* abase = At + (lane & 15) * ASTR + ((lane >> 4) << 3);
        f32x4 acc0 = {0.f, 0.f, 0.f, 0.f};
#pragma unroll 4
        for (int ks = 0; ks < NKS; ++ks) {
            half8v ah = *(const half8v*)(abase + ks * 32);
            size_t bb = (size_t)(ks * 4 + w) * 64 + lane;
            half8v bh = Bh8[bb];
            half8v bl = Bl8[bb];
            acc0 = __builtin_amdgcn_mfma_f32_16x16x32_f16(ah, bh, acc0, 0, 0, 0);
            acc0 = __builtin_amdgcn_mfma_f32_16x16x32_f16(ah, bl, acc0, 0, 0, 0);
        }

        // epilogue: D layout col=lane&15, row=(lane>>4)*4+j
        int colb = lane & 15, kg = lane >> 4;
        int c = w * 16 + colb;
        float bv = bias[c];
#pragma unroll
        for (int j = 0; j < 4; j++) {
            int rl = kg * 4 + j;
            int row = nb0 + rl;
            if (row < N) {
                float v = acc0[j] + bv;
                if (act) v = v > 0.f ? v : 0.f;
                if (out) out[(size_t)row * DD + c] = v;
                if (hout16) hout16[(size_t)row * DD + c] = (_Float16)v;
                if (doEWn) Hf[rl * 68 + c] = v;
            }
        }
    }

    // ---- EW epilogue: next layer's (ev, ev*gate) from fp32 tile, all-LDS ----
    if (doEWn) {
        __syncthreads();
        if (tid < TROWS * RR) {
            int nl = tid / RR, r = tid - nl * RR;
            int node = nb0 + nl;
            if (node < N) {
                const float* hp = Hf + nl * 68;
                const float* qp = qg + r * 68;
                const float* gp = qg + 816 + r * 68;
                float aq = 0.f, ag = 0.f;
#pragma unroll
                for (int c4 = 0; c4 < 16; c4++) {
                    float4 hv = *(const float4*)(hp + c4 * 4);
                    float4 qv = *(const float4*)(qp + c4 * 4);
                    float4 gv = *(const float4*)(gp + c4 * 4);
                    aq += hv.x * qv.x + hv.y * qv.y + hv.z * qv.z + hv.w * qv.w;
                    ag += hv.x * gv.x + hv.y * gv.y + hv.z * gv.z + hv.w * gv.w;
                }
                float sc = aq > 0.f ? aq : 0.01f * aq;
                float ev = expf(sc);
                float gate = 1.f / (1.f + expf(-(ag + gbn[0])));
                EWtab[(size_t)node * RR + r] = make_float2(ev, ev * gate);
            }
        }
    }
}

extern "C" void kernel_launch(void* const* d_in, const int* in_sizes, int n_in,
                              void* d_out, int out_size, void* d_ws, size_t ws_size,
                              hipStream_t stream) {
    const float* x    = (const float*)d_in[0];
    const int*   src  = (const int*)d_in[1];
    const int*   dst  = (const int*)d_in[2];
    const int*   etyp = (const int*)d_in[3];
    const float* Wemb = (const float*)d_in[4];
    const float* bemb = (const float*)d_in[5];
    const int N = in_sizes[0];
    const int E = in_sizes[1];
    const int nbuck = (N + 127) >> 7;
    const int nblk2 = (E + EPB2 - 1) / EPB2;

    const float* Wrel[3];  const float* Wself[3]; const float* bb[3];
    const float* gwv[3];   const float* gbv[3];   const float* av[3];
    for (int l = 0; l < 3; l++) {
        int o = 6 + 6 * l;
        Wrel[l]  = (const float*)d_in[o + 0];
        Wself[l] = (const float*)d_in[o + 1];
        bb[l]    = (const float*)d_in[o + 2];
        gwv[l]   = (const float*)d_in[o + 3];
        gbv[l]   = (const float*)d_in[o + 4];
        av[l]    = (const float*)d_in[o + 5];
    }
    const float* Wskip[3] = { nullptr, (const float*)d_in[24], (const float*)d_in[25] };

    // ---- workspace ----
    float* p = (float*)d_ws;
    _Float16* h16A = (_Float16*)p; p += (size_t)N * DD / 2;   // fp16 copy (ping)
    _Float16* h16B = (_Float16*)p; p += (size_t)N * DD / 2;   // fp16 copy (pong)
    float2* EW = (float2*)p; p += (size_t)N * RR * 2;
    unsigned short* cnt16 = (unsigned short*)p; p += ((size_t)N * RR + 1) / 2;
    float* qv3[3]; float* gv3[3]; _Float16* Bh3[3]; _Float16* Bl3[3];
    for (int l = 0; l < 3; l++) {
        qv3[l] = p; p += RR * DD;
        gv3[l] = p; p += RR * DD;
        Bh3[l] = (_Float16*)p; p += NKS * 4 * 64 * 8 / 2;
        Bl3[l] = (_Float16*)p; p += NKS * 4 * 64 * 8 / 2;
    }
    unsigned* epk2 = (unsigned*)p; p += E;
    unsigned* epk  = (unsigned*)p; p += E;
    float* wEv = p; p += E;
    int* bcnt  = (int*)p; p += 512;
    int* bbase = (int*)p; p += 516;
    int* bcur  = (int*)p; p += 512;
    int* offd  = (int*)p; p += N + 4;

    const int B = 256;

    // weight prep for all 3 layers upfront (independent of h)
    for (int l = 0; l < 3; l++)
        k_wprep<<<NKS + 3, B, 0, stream>>>(Wrel[l], Wself[l], Wskip[l], av[l], gwv[l],
                                           Bh3[l], Bl3[l], qv3[l], gv3[l]);

    k_h0<<<(N * DD + B - 1) / B, B, 0, stream>>>(x, Wemb, bemb, h16A, N);

    // coalesced two-level dst-sort (once; reused by all layers)
    hipMemsetAsync(bcnt, 0, 512 * 4, stream);
    k_bh<<<nblk2, 512, 0, stream>>>(dst, bcnt, E, nbuck);
    k_bscan<<<1, 512, 0, stream>>>(bcnt, bbase, bcur, nbuck, E);
    k_bscat<<<nblk2, 512, 0, stream>>>(src, dst, etyp, bcur, epk2, E, nbuck);
    k_b2<<<nbuck, 256, 0, stream>>>(epk2, bbase, epk, offd, cnt16, N, E);

    // layer 1's EW straight from x (no h0 f32 array)
    k_sgw2<<<(N * RR + B - 1) / B, B, 0, stream>>>(x, Wemb, bemb, qv3[0], gv3[0],
                                                   gbv[0], EW, N);

    const int fblocks = (N + TROWS - 1) / TROWS;
    const int eblocks = (E + B - 1) / B;

    // layer 1: in h16A, out h16B; EW for layer 2 computed in-epilogue
    k_ew<<<eblocks, B, 0, stream>>>(epk, EW, wEv, E);
    k_fused<<<fblocks, 512, 0, stream>>>(epk, offd, h16A, wEv, EW, cnt16,
                                         Bh3[0], Bl3[0], bb[0], nullptr, h16B,
                                         N, 1, 1, qv3[1], gv3[1], gbv[1]);
    // layer 2: in h16B, out h16A; EW for layer 3 computed in-epilogue
    k_ew<<<eblocks, B, 0, stream>>>(epk, EW, wEv, E);
    k_fused<<<fblocks, 512, 0, stream>>>(epk, offd, h16B, wEv, EW, cnt16,
                                         Bh3[1], Bl3[1], bb[1], nullptr, h16A,
                                         N, 1, 1, qv3[2], gv3[2], gbv[2]);
    // layer 3: in h16A, out d_out f32, no act, no EW epilogue
    k_ew<<<eblocks, B, 0, stream>>>(epk, EW, wEv, E);
    k_fused<<<fblocks, 512, 0, stream>>>(epk, offd, h16A, wEv, EW, cnt16,
                                         Bh3[2], Bl3[2], bb[2], (float*)d_out, nullptr,
                                         N, 0, 0, nullptr, nullptr, nullptr);
}